// Round 4
// baseline (1675.204 us; speedup 1.0000x reference)
//
#include <hip/hip_runtime.h>
#include <hip/hip_bf16.h>
#include <math.h>

#define N_NODES 50000
#define N_EDGES 800000
#define FDIM 53
#define BATCH 128
#define HF 212   /* H*F */
#define F2 106   /* 2F  */
#define POOLW 424 /* 212+106+106 */
#define NPACK 432 /* 212 + 106 + 106 + 8 */

typedef __attribute__((ext_vector_type(8))) short short8;
typedef __attribute__((ext_vector_type(4))) float f32x4;

__device__ __forceinline__ float leaky02(float x){ return x >= 0.f ? x : 0.2f * x; }

// fp32 -> bf16 (RNE) bit helpers
__device__ __forceinline__ short f2bf(float x) {
  unsigned u = __float_as_uint(x);
  unsigned r = (u + 0x7fffu + ((u >> 16) & 1u)) >> 16;
  return (short)r;
}
__device__ __forceinline__ float bf2f(short b) {
  return __uint_as_float(((unsigned)(unsigned short)b) << 16);
}
// packed pair f32x2 -> bf16x2 (v_cvt_pk_bf16_f32, RNE)
__device__ __forceinline__ unsigned pk2(float a, float b) {
  union { __hip_bfloat162 h; unsigned u; } c;
  c.h = __float22bfloat162_rn(make_float2(a, b));
  return c.u;
}

// ---------------------------------------------------------------------------
// cAl[k*8 + sd*4 + h] = sum_f gat_w[k, h*53+f] * (sd? a_dst : a_src)[h,f]
// ---------------------------------------------------------------------------
__global__ void k_cal(const float* __restrict__ gat_w, const float* __restrict__ asrc,
                      const float* __restrict__ adst, float* __restrict__ cAl) {
  int t = threadIdx.x;
  if (t >= FDIM * 8) return;
  int k = t >> 3, r = t & 7, sd = r >> 2, h = r & 3;
  const float* av = sd ? adst : asrc;
  float acc = 0.f;
  for (int f = 0; f < FDIM; ++f) acc += gat_w[k * HF + h * FDIM + f] * av[h * FDIM + f];
  cAl[t] = acc;
}

// ---------------------------------------------------------------------------
// Pack Wp[53][432] = [gat_w | W1top-W1bot | W1bot | cAl] and bias bp[432]
// ---------------------------------------------------------------------------
__global__ void k_prep(const float* __restrict__ gat_w, const float* __restrict__ ec_w1,
                       const float* __restrict__ ec_b1, const float* __restrict__ cAl,
                       float* __restrict__ Wp, float* __restrict__ bp) {
  int idx = blockIdx.x * blockDim.x + threadIdx.x;
  if (idx < FDIM * NPACK) {
    int k = idx / NPACK, j = idx % NPACK;
    float v;
    if (j < HF)            v = gat_w[k * HF + j];
    else if (j < HF + F2)  v = ec_w1[k * F2 + (j - HF)] - ec_w1[(FDIM + k) * F2 + (j - HF)];
    else if (j < POOLW)    v = ec_w1[(FDIM + k) * F2 + (j - HF - F2)];
    else                   v = cAl[k * 8 + (j - POOLW)];
    Wp[idx] = v;
  }
  if (idx < NPACK) {
    bp[idx] = (idx >= HF && idx < HF + F2) ? ec_b1[idx - HF] : 0.f;
  }
}

// ---------------------------------------------------------------------------
// Node-linear as tiled fp32 GEMM: x[50000x53] @ Wp[53x432] + bp.
// ---------------------------------------------------------------------------
#define GM 64
#define GN 144
#define APAD 57
__global__ __launch_bounds__(256) void k_gemm(
    const float* __restrict__ x, const float* __restrict__ Wp, const float* __restrict__ bp,
    float* __restrict__ xh, float* __restrict__ U, float* __restrict__ V,
    float* __restrict__ alS, float* __restrict__ alD) {
  __shared__ float As[GM * APAD];
  __shared__ float Ws[FDIM * GN];
  int mb = blockIdx.x / 3, nc = blockIdx.x % 3;
  int m0 = mb * GM, n0 = nc * GN;
  int t = threadIdx.x;
  for (int idx = t; idx < GM * FDIM; idx += 256) {
    int m = idx / FDIM, k = idx % FDIM;
    int gm = m0 + m;
    As[m * APAD + k] = (gm < N_NODES) ? x[(size_t)gm * FDIM + k] : 0.f;
  }
  for (int idx = t; idx < FDIM * GN; idx += 256) {
    int k = idx / GN, n = idx % GN;
    Ws[idx] = Wp[k * NPACK + n0 + n];
  }
  __syncthreads();
  int tx = t & 15, ty = t >> 4;
  int ms = tx * 4, ns = ty * 9;
  float acc[4][9];
#pragma unroll
  for (int i = 0; i < 4; i++)
#pragma unroll
    for (int j = 0; j < 9; j++) acc[i][j] = 0.f;
  for (int k = 0; k < FDIM; k++) {
    float a0 = As[(ms + 0) * APAD + k];
    float a1 = As[(ms + 1) * APAD + k];
    float a2 = As[(ms + 2) * APAD + k];
    float a3 = As[(ms + 3) * APAD + k];
    float b[9];
#pragma unroll
    for (int j = 0; j < 9; j++) b[j] = Ws[k * GN + ns + j];
#pragma unroll
    for (int j = 0; j < 9; j++) {
      acc[0][j] += a0 * b[j];
      acc[1][j] += a1 * b[j];
      acc[2][j] += a2 * b[j];
      acc[3][j] += a3 * b[j];
    }
  }
  float bj[9];
#pragma unroll
  for (int j = 0; j < 9; j++) bj[j] = bp[n0 + ns + j];
#pragma unroll
  for (int i = 0; i < 4; i++) {
    int gm = m0 + ms + i;
    if (gm >= N_NODES) break;
#pragma unroll
    for (int j = 0; j < 9; j++) {
      int g = n0 + ns + j;
      float v = acc[i][j] + bj[j];
      if (g < HF)            xh[(size_t)gm * HF + g] = v;
      else if (g < HF + F2)  U[(size_t)gm * F2 + (g - HF)] = v;
      else if (g < POOLW)    V[(size_t)gm * F2 + (g - HF - F2)] = v;
      else if (g < POOLW + 4) alS[gm * 4 + (g - POOLW)] = v;
      else                   alD[gm * 4 + (g - POOLW - 4)] = v;
    }
  }
}

// ---------------------------------------------------------------------------
// CSR build: histogram, 3-phase multi-block scan, scatter
// ---------------------------------------------------------------------------
#define SCAN_BLOCKS ((N_NODES + 255) / 256)

__global__ void k_hist(const int* __restrict__ ei, const int* __restrict__ batch,
                       int* __restrict__ rp, int* __restrict__ cnt) {
  int t = blockIdx.x * blockDim.x + threadIdx.x;
  if (t < N_EDGES) atomicAdd(&rp[ei[N_EDGES + t]], 1);
  if (t < N_NODES) atomicAdd(&cnt[batch[t]], 1);
}

__global__ __launch_bounds__(256) void k_scan1(int* __restrict__ rp, int* __restrict__ bsum) {
  __shared__ int buf[256];
  int tid = threadIdx.x;
  int idx = blockIdx.x * 256 + tid;
  int v = (idx < N_NODES) ? rp[idx] : 0;
  buf[tid] = v;
  __syncthreads();
  for (int off = 1; off < 256; off <<= 1) {
    int t2 = (tid >= off) ? buf[tid - off] : 0;
    __syncthreads();
    buf[tid] += t2;
    __syncthreads();
  }
  if (idx < N_NODES) rp[idx] = buf[tid] - v;
  if (tid == 255) bsum[blockIdx.x] = buf[255];
}

__global__ __launch_bounds__(256) void k_scan2(int* __restrict__ bsum) {
  __shared__ int buf[256];
  int tid = threadIdx.x;
  int v = (tid < SCAN_BLOCKS) ? bsum[tid] : 0;
  buf[tid] = v;
  __syncthreads();
  for (int off = 1; off < 256; off <<= 1) {
    int t2 = (tid >= off) ? buf[tid - off] : 0;
    __syncthreads();
    buf[tid] += t2;
    __syncthreads();
  }
  if (tid < SCAN_BLOCKS) bsum[tid] = buf[tid] - v;
}

__global__ __launch_bounds__(256) void k_scan3(const int* __restrict__ bsum,
                                               int* __restrict__ rp, int* __restrict__ cursor) {
  int idx = blockIdx.x * 256 + threadIdx.x;
  if (idx < N_NODES) {
    int o = rp[idx] + bsum[blockIdx.x];
    rp[idx] = o;
    cursor[idx] = o;
  }
  if (idx == 0) rp[N_NODES] = N_EDGES;
}

__global__ void k_scatter(const int* __restrict__ ei, int* __restrict__ cursor,
                          int* __restrict__ colidx) {
  int e = blockIdx.x * blockDim.x + threadIdx.x;
  if (e >= N_EDGES) return;
  int d = ei[N_EDGES + e];
  int pos = atomicAdd(&cursor[d], 1);
  colidx[pos] = ei[e];
}

// ---------------------------------------------------------------------------
// GAT: wave per node
// ---------------------------------------------------------------------------
__global__ __launch_bounds__(256) void k_gat(
    const float* __restrict__ xh, const float* __restrict__ alS, const float* __restrict__ alD,
    const float* __restrict__ bias, const int* __restrict__ rp, const int* __restrict__ colidx,
    const int* __restrict__ batch, float* __restrict__ pooled) {
  int wid = threadIdx.x >> 6, lane = threadIdx.x & 63;
  int i = blockIdx.x * 4 + wid;
  if (i >= N_NODES) return;
  int base = rp[i], deg = rp[i + 1] - base;
  float aldi[4], esf[4];
#pragma unroll
  for (int h = 0; h < 4; h++) {
    aldi[h] = alD[i * 4 + h];
    esf[h] = leaky02(alS[i * 4 + h] + aldi[h]);
  }
  float mx[4] = {-1e30f, -1e30f, -1e30f, -1e30f};
  for (int c = lane; c < deg; c += 64) {
    int s = colidx[base + c];
#pragma unroll
    for (int h = 0; h < 4; h++) mx[h] = fmaxf(mx[h], leaky02(alS[s * 4 + h] + aldi[h]));
  }
#pragma unroll
  for (int off = 32; off >= 1; off >>= 1)
#pragma unroll
    for (int h = 0; h < 4; h++) mx[h] = fmaxf(mx[h], __shfl_xor(mx[h], off));
  float m[4], exs[4];
#pragma unroll
  for (int h = 0; h < 4; h++) { m[h] = fmaxf(mx[h], esf[h]); exs[h] = __expf(esf[h] - m[h]); }

  int f0 = lane, f1 = lane + 64, f2 = lane + 128, f3 = lane + 192;
  bool v3 = (f3 < HF);
  bool h0a = f0 < FDIM;
  bool h1a = f1 < 2 * FDIM;
  bool h2a = f2 < 3 * FDIM;
  const float* xhi = xh + (size_t)i * HF;
  float acc0 = (h0a ? exs[0] : exs[1]) * xhi[f0];
  float acc1 = (h1a ? exs[1] : exs[2]) * xhi[f1];
  float acc2 = (h2a ? exs[2] : exs[3]) * xhi[f2];
  float acc3 = v3 ? exs[3] * xhi[f3] : 0.f;
  float zl[4] = {0.f, 0.f, 0.f, 0.f};

  for (int c0 = 0; c0 < deg; c0 += 64) {
    int cn = min(64, deg - c0);
    int s = 0;
    float ex0 = 0.f, ex1 = 0.f, ex2 = 0.f, ex3 = 0.f;
    if (lane < cn) {
      s = colidx[base + c0 + lane];
      ex0 = __expf(leaky02(alS[s * 4 + 0] + aldi[0]) - m[0]);
      ex1 = __expf(leaky02(alS[s * 4 + 1] + aldi[1]) - m[1]);
      ex2 = __expf(leaky02(alS[s * 4 + 2] + aldi[2]) - m[2]);
      ex3 = __expf(leaky02(alS[s * 4 + 3] + aldi[3]) - m[3]);
      zl[0] += ex0; zl[1] += ex1; zl[2] += ex2; zl[3] += ex3;
    }
    for (int jj = 0; jj < cn; jj++) {
      int sj = __shfl(s, jj);
      float a0 = __shfl(ex0, jj), a1 = __shfl(ex1, jj);
      float a2 = __shfl(ex2, jj), a3 = __shfl(ex3, jj);
      const float* xr = xh + (size_t)sj * HF;
      acc0 += (h0a ? a0 : a1) * xr[f0];
      acc1 += (h1a ? a1 : a2) * xr[f1];
      acc2 += (h2a ? a2 : a3) * xr[f2];
      if (v3) acc3 += a3 * xr[f3];
    }
  }
#pragma unroll
  for (int off = 32; off >= 1; off >>= 1)
#pragma unroll
    for (int h = 0; h < 4; h++) zl[h] += __shfl_xor(zl[h], off);
  float z[4];
#pragma unroll
  for (int h = 0; h < 4; h++) z[h] = zl[h] + exs[h] + 1e-16f;

  int b = batch[i];
  float* pg = pooled + (size_t)b * POOLW;
  float o0 = fmaxf(acc0 / (h0a ? z[0] : z[1]) + bias[f0], 0.f);
  float o1 = fmaxf(acc1 / (h1a ? z[1] : z[2]) + bias[f1], 0.f);
  float o2 = fmaxf(acc2 / (h2a ? z[2] : z[3]) + bias[f2], 0.f);
  atomicAdd(&pg[f0], o0);
  atomicAdd(&pg[f1], o1);
  atomicAdd(&pg[f2], o2);
  if (v3) {
    float o3 = fmaxf(acc3 / z[3] + bias[f3], 0.f);
    atomicAdd(&pg[f3], o3);
  }
}

// ---------------------------------------------------------------------------
// GIN: wave per node, neighbor gather unrolled x4 for MLP
// ---------------------------------------------------------------------------
__global__ __launch_bounds__(256) void k_gin(
    const float* __restrict__ x, const float* __restrict__ w1, const float* __restrict__ b1,
    const float* __restrict__ w2, const float* __restrict__ b2,
    const int* __restrict__ rp, const int* __restrict__ colidx, const int* __restrict__ batch,
    float* __restrict__ pooled) {
  int wid = threadIdx.x >> 6, lane = threadIdx.x & 63;
  int i = blockIdx.x * 4 + wid;
  if (i >= N_NODES) return;
  int base = rp[i], deg = rp[i + 1] - base;
  float hk = (lane < FDIM) ? x[(size_t)i * FDIM + lane] : 0.f;
  int c = 0;
  for (; c + 4 <= deg; c += 4) {
    int s0 = colidx[base + c + 0];
    int s1 = colidx[base + c + 1];
    int s2 = colidx[base + c + 2];
    int s3 = colidx[base + c + 3];
    if (lane < FDIM) {
      float v0 = x[(size_t)s0 * FDIM + lane];
      float v1 = x[(size_t)s1 * FDIM + lane];
      float v2 = x[(size_t)s2 * FDIM + lane];
      float v3 = x[(size_t)s3 * FDIM + lane];
      hk += (v0 + v1) + (v2 + v3);
    }
  }
  for (; c < deg; c++) {
    int s = colidx[base + c];
    if (lane < FDIM) hk += x[(size_t)s * FDIM + lane];
  }
  int u = lane, u2 = lane + 64;
  int u2m = (u2 < F2) ? u2 : 0;
  float a1 = b1[u], a2 = b1[u2m];
#pragma unroll
  for (int k = 0; k < FDIM; k++) {
    float hb = __shfl(hk, k);
    a1 += hb * w1[k * F2 + u];
    a2 += hb * w1[k * F2 + u2m];
  }
  float h1a = fmaxf(a1, 0.f);
  float h1b = (u2 < F2) ? fmaxf(a2, 0.f) : 0.f;
  a1 = b2[u]; a2 = b2[u2m];
#pragma unroll
  for (int k = 0; k < F2; k++) {
    float hb = (k < 64) ? __shfl(h1a, k) : __shfl(h1b, k - 64);
    a1 += hb * w2[k * F2 + u];
    a2 += hb * w2[k * F2 + u2m];
  }
  int b = batch[i];
  float* pg = pooled + (size_t)b * POOLW + HF;
  atomicAdd(&pg[u], fmaxf(a1, 0.f));
  if (u2 < F2) atomicAdd(&pg[u2], fmaxf(a2, 0.f));
}

// ---------------------------------------------------------------------------
// EdgeConv v3: barrier-free MFMA. Each lane loads its own A-fragment
// (A[m=lane&15][k=quad*8+j]) straight from V's row: 8 consecutive dwords
// (float2 loads, 8B-aligned since 106*4 % 8 == 0). relu(U+V) + hi/lo bf16
// split in registers (v_cvt_pk_bf16_f32). No LDS, no __syncthreads, no bank
// conflicts. Edges >= deg need no A-mask: their garbage feeds only D rows
// discarded by the er<deg output mask. k >= 106 masked to 0 pre-convert
// (loads stray <=88B into next 256B-aligned ws block: safe).
// ---------------------------------------------------------------------------
__global__ __launch_bounds__(256) void k_ec(
    const float* __restrict__ U, const float* __restrict__ V,
    const float* __restrict__ w2, const float* __restrict__ b2,
    const int* __restrict__ rp, const int* __restrict__ colidx,
    const int* __restrict__ batch, float* __restrict__ pooled) {
  const int t = threadIdx.x;
  const int lane = t & 63, wid = t >> 6;
  const int n16 = lane & 15, quad = lane >> 4;
  const int nt = (wid == 3) ? 1 : 2;   // u-tile 7 is all-pad

  // --- B fragments (w2 split into bf16 hi/lo), once per block ---
  short8 Bhi[2][4], Blo[2][4];
  for (int tt = 0; tt < 2; tt++) {
    int ucol = (wid * 2 + tt) * 16 + n16;
    for (int kc = 0; kc < 4; kc++) {
      short8 vh, vl;
#pragma unroll
      for (int jv = 0; jv < 8; jv++) {
        int kk = kc * 32 + quad * 8 + jv;
        float w = (ucol < F2 && kk < F2) ? w2[kk * F2 + ucol] : 0.f;
        short h = f2bf(w);
        vh[jv] = h;
        vl[jv] = f2bf(w - bf2f(h));
      }
      Bhi[tt][kc] = vh; Blo[tt][kc] = vl;
    }
  }
  float b2v[2];
#pragma unroll
  for (int tt = 0; tt < 2; tt++) {
    int u = (wid * 2 + tt) * 16 + n16;
    b2v[tt] = (u < F2) ? b2[u] : 0.f;
  }

  union SU { short8 s; unsigned u[4]; };
  const int kb = quad * 8;   // this lane's k-offset within each 32-chunk

  for (int i = blockIdx.x; i < N_NODES; i += gridDim.x) {
    int base = rp[i], deg = rp[i + 1] - base;
    if (deg == 0) continue;
    // per-lane U values for this node (reused across all edge tiles)
    float Uv[4][8];
#pragma unroll
    for (int kc = 0; kc < 4; kc++) {
      const float2* up = (const float2*)(U + (size_t)i * F2 + kc * 32 + kb);
#pragma unroll
      for (int p = 0; p < 4; p++) {
        float2 v = up[p];
        Uv[kc][2 * p] = v.x; Uv[kc][2 * p + 1] = v.y;
      }
    }
    float vmax0 = -1e30f, vmax1 = -1e30f;
    int ntile = (deg + 15) >> 4;
    for (int tb = 0; tb < ntile; tb++) {
      int eg = tb * 16 + n16;
      int s = (eg < deg) ? colidx[base + eg] : 0;   // clamp index in-bounds
      const float* Vr = V + (size_t)s * F2;
      f32x4 a0 = {0.f, 0.f, 0.f, 0.f}, a1 = {0.f, 0.f, 0.f, 0.f};
#pragma unroll
      for (int kc = 0; kc < 4; kc++) {
        const float2* vp = (const float2*)(Vr + kc * 32 + kb);
        SU ah, al;
#pragma unroll
        for (int p = 0; p < 4; p++) {
          float2 v = vp[p];
          int k0 = kc * 32 + kb + 2 * p;
          float h0 = 0.f, h1 = 0.f;
          if (k0 < F2) {   // pairs never straddle 106 (even boundary)
            h0 = fmaxf(Uv[kc][2 * p] + v.x, 0.f);
            h1 = fmaxf(Uv[kc][2 * p + 1] + v.y, 0.f);
          }
          unsigned hi = pk2(h0, h1);
          float r0 = h0 - __uint_as_float(hi << 16);
          float r1 = h1 - __uint_as_float(hi & 0xffff0000u);
          unsigned lo = pk2(r0, r1);
          ah.u[p] = hi; al.u[p] = lo;
        }
        a0 = __builtin_amdgcn_mfma_f32_16x16x32_bf16(ah.s, Bhi[0][kc], a0, 0, 0, 0);
        a0 = __builtin_amdgcn_mfma_f32_16x16x32_bf16(al.s, Bhi[0][kc], a0, 0, 0, 0);
        a0 = __builtin_amdgcn_mfma_f32_16x16x32_bf16(ah.s, Blo[0][kc], a0, 0, 0, 0);
        if (nt > 1) {
          a1 = __builtin_amdgcn_mfma_f32_16x16x32_bf16(ah.s, Bhi[1][kc], a1, 0, 0, 0);
          a1 = __builtin_amdgcn_mfma_f32_16x16x32_bf16(al.s, Bhi[1][kc], a1, 0, 0, 0);
          a1 = __builtin_amdgcn_mfma_f32_16x16x32_bf16(ah.s, Blo[1][kc], a1, 0, 0, 0);
        }
      }
      float m0 = -1e30f, m1 = -1e30f;
#pragma unroll
      for (int r = 0; r < 4; r++) {
        int er = tb * 16 + quad * 4 + r;   // D rows: m = quad*4 + reg
        if (er < deg) { m0 = fmaxf(m0, a0[r]); m1 = fmaxf(m1, a1[r]); }
      }
      m0 = fmaxf(m0, __shfl_xor(m0, 16)); m0 = fmaxf(m0, __shfl_xor(m0, 32));
      m1 = fmaxf(m1, __shfl_xor(m1, 16)); m1 = fmaxf(m1, __shfl_xor(m1, 32));
      vmax0 = fmaxf(vmax0, m0);
      vmax1 = fmaxf(vmax1, m1);
    }
    if (quad == 0) {
      int b = batch[i];
      float* pg = pooled + (size_t)b * POOLW + HF + F2;
      int u0 = (wid * 2) * 16 + n16;
      if (u0 < F2) atomicAdd(&pg[u0], fmaxf(vmax0 + b2v[0], 0.f));
      int u1 = (wid * 2 + 1) * 16 + n16;
      if (nt > 1 && u1 < F2) atomicAdd(&pg[u1], fmaxf(vmax1 + b2v[1], 0.f));
    }
  }
}

// ---------------------------------------------------------------------------
// mean-pool divide, generic small dense
// ---------------------------------------------------------------------------
__global__ void k_pooldiv(float* __restrict__ pooled, const int* __restrict__ cnt) {
  int t = blockIdx.x * blockDim.x + threadIdx.x;
  if (t >= BATCH * POOLW) return;
  int b = t / POOLW;
  pooled[t] /= fmaxf((float)cnt[b], 1.f);
}

__global__ void k_dense(const float* __restrict__ A, int lda, const float* __restrict__ W,
                        const float* __restrict__ bias, float* __restrict__ C, int ldc,
                        int M, int K, int N, int act) {
  int t = blockIdx.x * blockDim.x + threadIdx.x;
  if (t >= M * N) return;
  int mm = t / N, nn = t % N;
  float acc = bias[nn];
  for (int k = 0; k < K; k++) acc += A[(size_t)mm * lda + k] * W[(size_t)k * N + nn];
  if (act == 1) acc = fmaxf(acc, 0.f);
  else if (act == 2) acc = 1.f / (1.f + __expf(-acc));
  C[(size_t)mm * ldc + nn] = acc;
}

// ---------------------------------------------------------------------------
extern "C" void kernel_launch(void* const* d_in, const int* in_sizes, int n_in,
                              void* d_out, int out_size, void* d_ws, size_t ws_size,
                              hipStream_t stream) {
  const float* x      = (const float*)d_in[0];
  const int*   ei     = (const int*)d_in[1];
  const int*   batch  = (const int*)d_in[2];
  const float* gat_w  = (const float*)d_in[3];
  const float* asrc   = (const float*)d_in[4];
  const float* adst   = (const float*)d_in[5];
  const float* gat_b  = (const float*)d_in[6];
  const float* gin_w1 = (const float*)d_in[7];
  const float* gin_b1 = (const float*)d_in[8];
  const float* gin_w2 = (const float*)d_in[9];
  const float* gin_b2 = (const float*)d_in[10];
  const float* ec_w1  = (const float*)d_in[11];
  const float* ec_b1  = (const float*)d_in[12];
  const float* ec_w2  = (const float*)d_in[13];
  const float* ec_b2  = (const float*)d_in[14];
  const float* fg1_w = (const float*)d_in[15]; const float* fg1_b = (const float*)d_in[16];
  const float* fg2_w = (const float*)d_in[17]; const float* fg2_b = (const float*)d_in[18];
  const float* fg3_w = (const float*)d_in[19]; const float* fg3_b = (const float*)d_in[20];
  const float* fg4_w = (const float*)d_in[21]; const float* fg4_b = (const float*)d_in[22];
  const float* fg5_w = (const float*)d_in[23]; const float* fg5_b = (const float*)d_in[24];
  const float* fg6_w = (const float*)d_in[25]; const float* fg6_b = (const float*)d_in[26];
  const float* fc1_w = (const float*)d_in[27]; const float* fc1_b = (const float*)d_in[28];
  const float* fc2_w = (const float*)d_in[29]; const float* fc2_b = (const float*)d_in[30];
  const float* out_w = (const float*)d_in[31]; const float* out_b = (const float*)d_in[32];
  float* out = (float*)d_out;

  char* ws = (char*)d_ws;
  size_t off = 0;
  auto alloc = [&](size_t bytes) -> void* {
    void* p = ws + off;
    off = (off + bytes + 255) & ~(size_t)255;
    return p;
  };
  // --- zero region (one memset): rp | cnt | pooled ---
  size_t zoff0 = off;
  int*   rp     = (int*)alloc((N_NODES + 1) * sizeof(int));
  int*   cnt    = (int*)alloc(BATCH * sizeof(int));
  float* pooled = (float*)alloc((size_t)BATCH * POOLW * sizeof(float));
  size_t zbytes = off - zoff0;
  // --- rest ---
  int*   cursor = (int*)alloc(N_NODES * sizeof(int));
  int*   bsum   = (int*)alloc(256 * sizeof(int));
  int*   colidx = (int*)alloc(N_EDGES * sizeof(int));
  float* xh     = (float*)alloc((size_t)N_NODES * HF * sizeof(float));
  float* alS    = (float*)alloc((size_t)N_NODES * 4 * sizeof(float));
  float* alD    = (float*)alloc((size_t)N_NODES * 4 * sizeof(float));
  float* Ubuf   = (float*)alloc((size_t)N_NODES * F2 * sizeof(float));
  float* Vbuf   = (float*)alloc((size_t)N_NODES * F2 * sizeof(float));
  float* cAl    = (float*)alloc(FDIM * 8 * sizeof(float));
  float* Wp     = (float*)alloc((size_t)FDIM * NPACK * sizeof(float));
  float* bpk    = (float*)alloc(NPACK * sizeof(float));
  float* t1     = (float*)alloc((size_t)BATCH * 256 * sizeof(float));
  float* cat    = (float*)alloc((size_t)BATCH * 384 * sizeof(float));
  float* t3     = (float*)alloc((size_t)BATCH * 128 * sizeof(float));
  float* t4     = (float*)alloc((size_t)BATCH * 64 * sizeof(float));
  (void)ws_size; (void)in_sizes; (void)n_in; (void)out_size;

  hipMemsetAsync(ws + zoff0, 0, zbytes, stream);

  k_cal<<<1, 448, 0, stream>>>(gat_w, asrc, adst, cAl);
  k_prep<<<(FDIM * NPACK + 255) / 256, 256, 0, stream>>>(gat_w, ec_w1, ec_b1, cAl, Wp, bpk);
  k_gemm<<<((N_NODES + GM - 1) / GM) * 3, 256, 0, stream>>>(x, Wp, bpk,
                                                            xh, Ubuf, Vbuf, alS, alD);
  k_hist<<<(N_EDGES + 255) / 256, 256, 0, stream>>>(ei, batch, rp, cnt);
  k_scan1<<<SCAN_BLOCKS, 256, 0, stream>>>(rp, bsum);
  k_scan2<<<1, 256, 0, stream>>>(bsum);
  k_scan3<<<SCAN_BLOCKS, 256, 0, stream>>>(bsum, rp, cursor);
  k_scatter<<<(N_EDGES + 255) / 256, 256, 0, stream>>>(ei, cursor, colidx);

  k_gat<<<(N_NODES + 3) / 4, 256, 0, stream>>>(xh, alS, alD, gat_b, rp, colidx, batch, pooled);
  k_gin<<<(N_NODES + 3) / 4, 256, 0, stream>>>(x, gin_w1, gin_b1, gin_w2, gin_b2,
                                               rp, colidx, batch, pooled);
  k_ec<<<2048, 256, 0, stream>>>(Ubuf, Vbuf, ec_w2, ec_b2, rp, colidx, batch, pooled);

  k_pooldiv<<<(BATCH * POOLW + 255) / 256, 256, 0, stream>>>(pooled, cnt);

  // heads: gat | gin | ec -> cat[128,384]
  k_dense<<<(128 * 256 + 255) / 256, 256, 0, stream>>>(pooled + 0, POOLW, fg1_w, fg1_b, t1, 256, 128, HF, 256, 1);
  k_dense<<<(128 * 128 + 255) / 256, 256, 0, stream>>>(t1, 256, fg2_w, fg2_b, cat + 0, 384, 128, 256, 128, 1);
  k_dense<<<(128 * 256 + 255) / 256, 256, 0, stream>>>(pooled + HF, POOLW, fg3_w, fg3_b, t1, 256, 128, F2, 256, 1);
  k_dense<<<(128 * 128 + 255) / 256, 256, 0, stream>>>(t1, 256, fg4_w, fg4_b, cat + 128, 384, 128, 256, 128, 1);
  k_dense<<<(128 * 256 + 255) / 256, 256, 0, stream>>>(pooled + HF + F2, POOLW, fg5_w, fg5_b, t1, 256, 128, F2, 256, 1);
  k_dense<<<(128 * 128 + 255) / 256, 256, 0, stream>>>(t1, 256, fg6_w, fg6_b, cat + 256, 384, 128, 256, 128, 1);
  // final MLP
  k_dense<<<(128 * 128 + 255) / 256, 256, 0, stream>>>(cat, 384, fc1_w, fc1_b, t3, 128, 128, 384, 128, 1);
  k_dense<<<(128 * 64 + 255) / 256, 256, 0, stream>>>(t3, 128, fc2_w, fc2_b, t4, 64, 128, 128, 64, 1);
  k_dense<<<1, 128, 0, stream>>>(t4, 64, out_w, out_b, out, 1, 128, 64, 1, 2);
}

// Round 5
// 1598.693 us; speedup vs baseline: 1.0479x; 1.0479x over previous
//
#include <hip/hip_runtime.h>
#include <hip/hip_bf16.h>
#include <math.h>

#define N_NODES 50000
#define N_EDGES 800000
#define FDIM 53
#define BATCH 128
#define HF 212   /* H*F */
#define F2 106   /* 2F  */
#define POOLW 424 /* 212+106+106 */
#define NPACK 432 /* 212 + 106 + 106 + 8 */

typedef __attribute__((ext_vector_type(8))) short short8;
typedef __attribute__((ext_vector_type(4))) float f32x4;

__device__ __forceinline__ float leaky02(float x){ return x >= 0.f ? x : 0.2f * x; }

__device__ __forceinline__ short f2bf(float x) {
  unsigned u = __float_as_uint(x);
  unsigned r = (u + 0x7fffu + ((u >> 16) & 1u)) >> 16;
  return (short)r;
}
// packed pair f32x2 -> bf16x2 (v_cvt_pk_bf16_f32, RNE)
__device__ __forceinline__ unsigned pk2(float a, float b) {
  union { __hip_bfloat162 h; unsigned u; } c;
  c.h = __float22bfloat162_rn(make_float2(a, b));
  return c.u;
}

// ---------------------------------------------------------------------------
// cAl[k*8 + sd*4 + h] = sum_f gat_w[k, h*53+f] * (sd? a_dst : a_src)[h,f]
// ---------------------------------------------------------------------------
__global__ void k_cal(const float* __restrict__ gat_w, const float* __restrict__ asrc,
                      const float* __restrict__ adst, float* __restrict__ cAl) {
  int t = threadIdx.x;
  if (t >= FDIM * 8) return;
  int k = t >> 3, r = t & 7, sd = r >> 2, h = r & 3;
  const float* av = sd ? adst : asrc;
  float acc = 0.f;
  for (int f = 0; f < FDIM; ++f) acc += gat_w[k * HF + h * FDIM + f] * av[h * FDIM + f];
  cAl[t] = acc;
}

// ---------------------------------------------------------------------------
// Pack Wp[53][432] = [gat_w | W1top-W1bot | W1bot | cAl] and bias bp[432]
// ---------------------------------------------------------------------------
__global__ void k_prep(const float* __restrict__ gat_w, const float* __restrict__ ec_w1,
                       const float* __restrict__ ec_b1, const float* __restrict__ cAl,
                       float* __restrict__ Wp, float* __restrict__ bp) {
  int idx = blockIdx.x * blockDim.x + threadIdx.x;
  if (idx < FDIM * NPACK) {
    int k = idx / NPACK, j = idx % NPACK;
    float v;
    if (j < HF)            v = gat_w[k * HF + j];
    else if (j < HF + F2)  v = ec_w1[k * F2 + (j - HF)] - ec_w1[(FDIM + k) * F2 + (j - HF)];
    else if (j < POOLW)    v = ec_w1[(FDIM + k) * F2 + (j - HF - F2)];
    else                   v = cAl[k * 8 + (j - POOLW)];
    Wp[idx] = v;
  }
  if (idx < NPACK) {
    bp[idx] = (idx >= HF && idx < HF + F2) ? ec_b1[idx - HF] : 0.f;
  }
}

// ---------------------------------------------------------------------------
// Node-linear as tiled fp32 GEMM: x[50000x53] @ Wp[53x432] + bp.
// ---------------------------------------------------------------------------
#define GM 64
#define GN 144
#define APAD 57
__global__ __launch_bounds__(256) void k_gemm(
    const float* __restrict__ x, const float* __restrict__ Wp, const float* __restrict__ bp,
    float* __restrict__ xh, float* __restrict__ U, float* __restrict__ V,
    float* __restrict__ alS, float* __restrict__ alD) {
  __shared__ float As[GM * APAD];
  __shared__ float Ws[FDIM * GN];
  int mb = blockIdx.x / 3, nc = blockIdx.x % 3;
  int m0 = mb * GM, n0 = nc * GN;
  int t = threadIdx.x;
  for (int idx = t; idx < GM * FDIM; idx += 256) {
    int m = idx / FDIM, k = idx % FDIM;
    int gm = m0 + m;
    As[m * APAD + k] = (gm < N_NODES) ? x[(size_t)gm * FDIM + k] : 0.f;
  }
  for (int idx = t; idx < FDIM * GN; idx += 256) {
    int k = idx / GN, n = idx % GN;
    Ws[idx] = Wp[k * NPACK + n0 + n];
  }
  __syncthreads();
  int tx = t & 15, ty = t >> 4;
  int ms = tx * 4, ns = ty * 9;
  float acc[4][9];
#pragma unroll
  for (int i = 0; i < 4; i++)
#pragma unroll
    for (int j = 0; j < 9; j++) acc[i][j] = 0.f;
  for (int k = 0; k < FDIM; k++) {
    float a0 = As[(ms + 0) * APAD + k];
    float a1 = As[(ms + 1) * APAD + k];
    float a2 = As[(ms + 2) * APAD + k];
    float a3 = As[(ms + 3) * APAD + k];
    float b[9];
#pragma unroll
    for (int j = 0; j < 9; j++) b[j] = Ws[k * GN + ns + j];
#pragma unroll
    for (int j = 0; j < 9; j++) {
      acc[0][j] += a0 * b[j];
      acc[1][j] += a1 * b[j];
      acc[2][j] += a2 * b[j];
      acc[3][j] += a3 * b[j];
    }
  }
  float bj[9];
#pragma unroll
  for (int j = 0; j < 9; j++) bj[j] = bp[n0 + ns + j];
#pragma unroll
  for (int i = 0; i < 4; i++) {
    int gm = m0 + ms + i;
    if (gm >= N_NODES) break;
#pragma unroll
    for (int j = 0; j < 9; j++) {
      int g = n0 + ns + j;
      float v = acc[i][j] + bj[j];
      if (g < HF)            xh[(size_t)gm * HF + g] = v;
      else if (g < HF + F2)  U[(size_t)gm * F2 + (g - HF)] = v;
      else if (g < POOLW)    V[(size_t)gm * F2 + (g - HF - F2)] = v;
      else if (g < POOLW + 4) alS[gm * 4 + (g - POOLW)] = v;
      else                   alD[gm * 4 + (g - POOLW - 4)] = v;
    }
  }
}

// ---------------------------------------------------------------------------
// CSR build: histogram, 3-phase multi-block scan, scatter
// ---------------------------------------------------------------------------
#define SCAN_BLOCKS ((N_NODES + 255) / 256)

__global__ void k_hist(const int* __restrict__ ei, const int* __restrict__ batch,
                       int* __restrict__ rp, int* __restrict__ cnt) {
  int t = blockIdx.x * blockDim.x + threadIdx.x;
  if (t < N_EDGES) atomicAdd(&rp[ei[N_EDGES + t]], 1);
  if (t < N_NODES) atomicAdd(&cnt[batch[t]], 1);
}

__global__ __launch_bounds__(256) void k_scan1(int* __restrict__ rp, int* __restrict__ bsum) {
  __shared__ int buf[256];
  int tid = threadIdx.x;
  int idx = blockIdx.x * 256 + tid;
  int v = (idx < N_NODES) ? rp[idx] : 0;
  buf[tid] = v;
  __syncthreads();
  for (int off = 1; off < 256; off <<= 1) {
    int t2 = (tid >= off) ? buf[tid - off] : 0;
    __syncthreads();
    buf[tid] += t2;
    __syncthreads();
  }
  if (idx < N_NODES) rp[idx] = buf[tid] - v;
  if (tid == 255) bsum[blockIdx.x] = buf[255];
}

__global__ __launch_bounds__(256) void k_scan2(int* __restrict__ bsum) {
  __shared__ int buf[256];
  int tid = threadIdx.x;
  int v = (tid < SCAN_BLOCKS) ? bsum[tid] : 0;
  buf[tid] = v;
  __syncthreads();
  for (int off = 1; off < 256; off <<= 1) {
    int t2 = (tid >= off) ? buf[tid - off] : 0;
    __syncthreads();
    buf[tid] += t2;
    __syncthreads();
  }
  if (tid < SCAN_BLOCKS) bsum[tid] = buf[tid] - v;
}

__global__ __launch_bounds__(256) void k_scan3(const int* __restrict__ bsum,
                                               int* __restrict__ rp, int* __restrict__ cursor) {
  int idx = blockIdx.x * 256 + threadIdx.x;
  if (idx < N_NODES) {
    int o = rp[idx] + bsum[blockIdx.x];
    rp[idx] = o;
    cursor[idx] = o;
  }
  if (idx == 0) rp[N_NODES] = N_EDGES;
}

__global__ void k_scatter(const int* __restrict__ ei, int* __restrict__ cursor,
                          int* __restrict__ colidx) {
  int e = blockIdx.x * blockDim.x + threadIdx.x;
  if (e >= N_EDGES) return;
  int d = ei[N_EDGES + e];
  int pos = atomicAdd(&cursor[d], 1);
  colidx[pos] = ei[e];
}

// ---------------------------------------------------------------------------
// GAT: wave per node
// ---------------------------------------------------------------------------
__global__ __launch_bounds__(256) void k_gat(
    const float* __restrict__ xh, const float* __restrict__ alS, const float* __restrict__ alD,
    const float* __restrict__ bias, const int* __restrict__ rp, const int* __restrict__ colidx,
    const int* __restrict__ batch, float* __restrict__ pooled) {
  int wid = threadIdx.x >> 6, lane = threadIdx.x & 63;
  int i = blockIdx.x * 4 + wid;
  if (i >= N_NODES) return;
  int base = rp[i], deg = rp[i + 1] - base;
  float aldi[4], esf[4];
#pragma unroll
  for (int h = 0; h < 4; h++) {
    aldi[h] = alD[i * 4 + h];
    esf[h] = leaky02(alS[i * 4 + h] + aldi[h]);
  }
  float mx[4] = {-1e30f, -1e30f, -1e30f, -1e30f};
  for (int c = lane; c < deg; c += 64) {
    int s = colidx[base + c];
#pragma unroll
    for (int h = 0; h < 4; h++) mx[h] = fmaxf(mx[h], leaky02(alS[s * 4 + h] + aldi[h]));
  }
#pragma unroll
  for (int off = 32; off >= 1; off >>= 1)
#pragma unroll
    for (int h = 0; h < 4; h++) mx[h] = fmaxf(mx[h], __shfl_xor(mx[h], off));
  float m[4], exs[4];
#pragma unroll
  for (int h = 0; h < 4; h++) { m[h] = fmaxf(mx[h], esf[h]); exs[h] = __expf(esf[h] - m[h]); }

  int f0 = lane, f1 = lane + 64, f2 = lane + 128, f3 = lane + 192;
  bool v3 = (f3 < HF);
  bool h0a = f0 < FDIM;
  bool h1a = f1 < 2 * FDIM;
  bool h2a = f2 < 3 * FDIM;
  const float* xhi = xh + (size_t)i * HF;
  float acc0 = (h0a ? exs[0] : exs[1]) * xhi[f0];
  float acc1 = (h1a ? exs[1] : exs[2]) * xhi[f1];
  float acc2 = (h2a ? exs[2] : exs[3]) * xhi[f2];
  float acc3 = v3 ? exs[3] * xhi[f3] : 0.f;
  float zl[4] = {0.f, 0.f, 0.f, 0.f};

  for (int c0 = 0; c0 < deg; c0 += 64) {
    int cn = min(64, deg - c0);
    int s = 0;
    float ex0 = 0.f, ex1 = 0.f, ex2 = 0.f, ex3 = 0.f;
    if (lane < cn) {
      s = colidx[base + c0 + lane];
      ex0 = __expf(leaky02(alS[s * 4 + 0] + aldi[0]) - m[0]);
      ex1 = __expf(leaky02(alS[s * 4 + 1] + aldi[1]) - m[1]);
      ex2 = __expf(leaky02(alS[s * 4 + 2] + aldi[2]) - m[2]);
      ex3 = __expf(leaky02(alS[s * 4 + 3] + aldi[3]) - m[3]);
      zl[0] += ex0; zl[1] += ex1; zl[2] += ex2; zl[3] += ex3;
    }
    for (int jj = 0; jj < cn; jj++) {
      int sj = __shfl(s, jj);
      float a0 = __shfl(ex0, jj), a1 = __shfl(ex1, jj);
      float a2 = __shfl(ex2, jj), a3 = __shfl(ex3, jj);
      const float* xr = xh + (size_t)sj * HF;
      acc0 += (h0a ? a0 : a1) * xr[f0];
      acc1 += (h1a ? a1 : a2) * xr[f1];
      acc2 += (h2a ? a2 : a3) * xr[f2];
      if (v3) acc3 += a3 * xr[f3];
    }
  }
#pragma unroll
  for (int off = 32; off >= 1; off >>= 1)
#pragma unroll
    for (int h = 0; h < 4; h++) zl[h] += __shfl_xor(zl[h], off);
  float z[4];
#pragma unroll
  for (int h = 0; h < 4; h++) z[h] = zl[h] + exs[h] + 1e-16f;

  int b = batch[i];
  float* pg = pooled + (size_t)b * POOLW;
  float o0 = fmaxf(acc0 / (h0a ? z[0] : z[1]) + bias[f0], 0.f);
  float o1 = fmaxf(acc1 / (h1a ? z[1] : z[2]) + bias[f1], 0.f);
  float o2 = fmaxf(acc2 / (h2a ? z[2] : z[3]) + bias[f2], 0.f);
  atomicAdd(&pg[f0], o0);
  atomicAdd(&pg[f1], o1);
  atomicAdd(&pg[f2], o2);
  if (v3) {
    float o3 = fmaxf(acc3 / z[3] + bias[f3], 0.f);
    atomicAdd(&pg[f3], o3);
  }
}

// ---------------------------------------------------------------------------
// GIN split: (1) gather-sum agg = x + sum_neighbors x  -> agg[50k x 53]
// ---------------------------------------------------------------------------
__global__ __launch_bounds__(256) void k_ginagg(
    const float* __restrict__ x, const int* __restrict__ rp, const int* __restrict__ colidx,
    float* __restrict__ agg) {
  int wid = threadIdx.x >> 6, lane = threadIdx.x & 63;
  int i = blockIdx.x * 4 + wid;
  if (i >= N_NODES) return;
  int base = rp[i], deg = rp[i + 1] - base;
  float hk = (lane < FDIM) ? x[(size_t)i * FDIM + lane] : 0.f;
  int c = 0;
  for (; c + 4 <= deg; c += 4) {
    int s0 = colidx[base + c + 0];
    int s1 = colidx[base + c + 1];
    int s2 = colidx[base + c + 2];
    int s3 = colidx[base + c + 3];
    if (lane < FDIM) {
      float v0 = x[(size_t)s0 * FDIM + lane];
      float v1 = x[(size_t)s1 * FDIM + lane];
      float v2 = x[(size_t)s2 * FDIM + lane];
      float v3 = x[(size_t)s3 * FDIM + lane];
      hk += (v0 + v1) + (v2 + v3);
    }
  }
  for (; c < deg; c++) {
    int s = colidx[base + c];
    if (lane < FDIM) hk += x[(size_t)s * FDIM + lane];
  }
  if (lane < FDIM) agg[(size_t)i * FDIM + lane] = hk;
}

// ---------------------------------------------------------------------------
// GIN (2): h1g = relu(agg @ w1 + b1), tiled fp32 GEMM 64x106, K=53
// ---------------------------------------------------------------------------
__global__ __launch_bounds__(256) void k_gin1(
    const float* __restrict__ agg, const float* __restrict__ w1, const float* __restrict__ b1,
    float* __restrict__ h1g) {
  __shared__ float As[64 * APAD];       // pad 57 (gcd(25,32)=1 -> conflict-free)
  __shared__ float Ws[FDIM * 112];
  int m0 = blockIdx.x * 64;
  int t = threadIdx.x;
  for (int idx = t; idx < 64 * FDIM; idx += 256) {
    int m = idx / FDIM, k = idx % FDIM;
    int gm = m0 + m;
    As[m * APAD + k] = (gm < N_NODES) ? agg[(size_t)gm * FDIM + k] : 0.f;
  }
  for (int idx = t; idx < FDIM * 112; idx += 256) {
    int k = idx / 112, n = idx % 112;
    Ws[idx] = (n < F2) ? w1[k * F2 + n] : 0.f;
  }
  __syncthreads();
  int tx = t & 15, ty = t >> 4;
  int ms = tx * 4, ns = ty * 7;
  float acc[4][7];
#pragma unroll
  for (int i = 0; i < 4; i++)
#pragma unroll
    for (int j = 0; j < 7; j++) acc[i][j] = 0.f;
  for (int k = 0; k < FDIM; k++) {
    float a0 = As[(ms + 0) * APAD + k];
    float a1 = As[(ms + 1) * APAD + k];
    float a2 = As[(ms + 2) * APAD + k];
    float a3 = As[(ms + 3) * APAD + k];
    float b[7];
#pragma unroll
    for (int j = 0; j < 7; j++) b[j] = Ws[k * 112 + ns + j];
#pragma unroll
    for (int j = 0; j < 7; j++) {
      acc[0][j] += a0 * b[j];
      acc[1][j] += a1 * b[j];
      acc[2][j] += a2 * b[j];
      acc[3][j] += a3 * b[j];
    }
  }
#pragma unroll
  for (int i = 0; i < 4; i++) {
    int gm = m0 + ms + i;
    if (gm >= N_NODES) break;
#pragma unroll
    for (int j = 0; j < 7; j++) {
      int n = ns + j;
      if (n < F2) h1g[(size_t)gm * F2 + n] = fmaxf(acc[i][j] + b1[n], 0.f);
    }
  }
}

// ---------------------------------------------------------------------------
// GIN (3): h2 = relu(h1g @ w2 + b2) with fused mean-pool atomicAdd. K=106.
// ---------------------------------------------------------------------------
#define A2PAD 111  /* gcd(111%32=15, 32)=1 -> conflict-free */
__global__ __launch_bounds__(256) void k_gin2(
    const float* __restrict__ h1g, const float* __restrict__ w2, const float* __restrict__ b2,
    const int* __restrict__ batch, float* __restrict__ pooled) {
  __shared__ float As[64 * A2PAD];
  __shared__ float Ws[F2 * 112];
  int m0 = blockIdx.x * 64;
  int t = threadIdx.x;
  for (int idx = t; idx < 64 * F2; idx += 256) {
    int m = idx / F2, k = idx % F2;
    int gm = m0 + m;
    As[m * A2PAD + k] = (gm < N_NODES) ? h1g[(size_t)gm * F2 + k] : 0.f;
  }
  for (int idx = t; idx < F2 * 112; idx += 256) {
    int k = idx / 112, n = idx % 112;
    Ws[idx] = (n < F2) ? w2[k * F2 + n] : 0.f;
  }
  __syncthreads();
  int tx = t & 15, ty = t >> 4;
  int ms = tx * 4, ns = ty * 7;
  float acc[4][7];
#pragma unroll
  for (int i = 0; i < 4; i++)
#pragma unroll
    for (int j = 0; j < 7; j++) acc[i][j] = 0.f;
  for (int k = 0; k < F2; k++) {
    float a0 = As[(ms + 0) * A2PAD + k];
    float a1 = As[(ms + 1) * A2PAD + k];
    float a2 = As[(ms + 2) * A2PAD + k];
    float a3 = As[(ms + 3) * A2PAD + k];
    float b[7];
#pragma unroll
    for (int j = 0; j < 7; j++) b[j] = Ws[k * 112 + ns + j];
#pragma unroll
    for (int j = 0; j < 7; j++) {
      acc[0][j] += a0 * b[j];
      acc[1][j] += a1 * b[j];
      acc[2][j] += a2 * b[j];
      acc[3][j] += a3 * b[j];
    }
  }
#pragma unroll
  for (int i = 0; i < 4; i++) {
    int gm = m0 + ms + i;
    if (gm >= N_NODES) break;
    int b = batch[gm];
    float* pg = pooled + (size_t)b * POOLW + HF;
#pragma unroll
    for (int j = 0; j < 7; j++) {
      int n = ns + j;
      if (n < F2) atomicAdd(&pg[n], fmaxf(acc[i][j] + b2[n], 0.f));
    }
  }
}

// ---------------------------------------------------------------------------
// EdgeConv v5: LDS-staged single-pass bf16 MFMA. Block(256)=4 waves/node.
// Per 16-edge tile: staging thread (es=t&15, kg=t>>4) loads V[s][kg*8..+7]
// (coalesced-ish float2), h1=relu(U+V) -> bf16 pairs, stored in FRAGMENT
// ORDER hs[(kg*16+es)*8 shorts]: a wave's b128 frag reads / staging writes
// each cover 256 consecutive dwords exactly once => conflict-free.
// One bf16 pass (A=bf16(h1), B=bf16(w2)): err ~3e-3 at h2 << 1.5e-2 thresh.
// ---------------------------------------------------------------------------
__global__ __launch_bounds__(256) void k_ec(
    const float* __restrict__ U, const float* __restrict__ V,
    const float* __restrict__ w2, const float* __restrict__ b2,
    const int* __restrict__ rp, const int* __restrict__ colidx,
    const int* __restrict__ batch, float* __restrict__ pooled) {
  const int t = threadIdx.x;
  const int lane = t & 63, wid = t >> 6;
  const int n16 = lane & 15, quad = lane >> 4;
  const int nt = (wid == 3) ? 1 : 2;   // u-tile 7 is all-pad

  // B fragments (bf16 hi only), once per block
  short8 Bh[2][4];
  for (int tt = 0; tt < 2; tt++) {
    int ucol = (wid * 2 + tt) * 16 + n16;
    for (int kc = 0; kc < 4; kc++) {
      short8 vh;
#pragma unroll
      for (int jv = 0; jv < 8; jv++) {
        int kk = kc * 32 + quad * 8 + jv;
        float w = (ucol < F2 && kk < F2) ? w2[kk * F2 + ucol] : 0.f;
        vh[jv] = f2bf(w);
      }
      Bh[tt][kc] = vh;
    }
  }
  float b2v[2];
#pragma unroll
  for (int tt = 0; tt < 2; tt++) {
    int u = (wid * 2 + tt) * 16 + n16;
    b2v[tt] = (u < F2) ? b2[u] : 0.f;
  }

  __shared__ short hs[16 * 16 * 8];   // [kg][es][8 shorts] = 4 KB
  union SU { short8 s; unsigned u[4]; };
  const int es = t & 15, kg = t >> 4;  // staging roles
  const int k0 = kg * 8;

  for (int i = blockIdx.x; i < N_NODES; i += gridDim.x) {
    int base = rp[i], deg = rp[i + 1] - base;
    if (deg == 0) continue;
    // per-thread U slice (float2: 8B-aligned since 106*i even)
    float Uv[8];
    {
      const float2* up = (const float2*)(U + (size_t)i * F2 + k0);
#pragma unroll
      for (int p = 0; p < 4; p++) { float2 v = up[p]; Uv[2*p] = v.x; Uv[2*p+1] = v.y; }
    }
    float vmax0 = -1e30f, vmax1 = -1e30f;
    int ntile = (deg + 15) >> 4;
    for (int tb = 0; tb < ntile; tb++) {
      int eg = tb * 16 + es;
      int s = (eg < deg) ? colidx[base + eg] : 0;
      const float2* vp = (const float2*)(V + (size_t)s * F2 + k0);
      SU w;
#pragma unroll
      for (int p = 0; p < 4; p++) {
        float2 v = vp[p];
        bool pv = (k0 + 2 * p) < F2;
        float h0 = pv ? fmaxf(Uv[2*p] + v.x, 0.f) : 0.f;
        float h1 = pv ? fmaxf(Uv[2*p+1] + v.y, 0.f) : 0.f;
        w.u[p] = pk2(h0, h1);
      }
      __syncthreads();                  // WAR: prev tile's frag reads done
      *(short8*)&hs[(kg * 16 + es) * 8] = w.s;
      __syncthreads();                  // RAW
      f32x4 a0 = {0.f, 0.f, 0.f, 0.f}, a1 = {0.f, 0.f, 0.f, 0.f};
#pragma unroll
      for (int kc = 0; kc < 4; kc++) {
        short8 af = *(const short8*)&hs[((kc * 4 + quad) * 16 + n16) * 8];
        a0 = __builtin_amdgcn_mfma_f32_16x16x32_bf16(af, Bh[0][kc], a0, 0, 0, 0);
        if (nt > 1)
          a1 = __builtin_amdgcn_mfma_f32_16x16x32_bf16(af, Bh[1][kc], a1, 0, 0, 0);
      }
      float m0 = -1e30f, m1 = -1e30f;
#pragma unroll
      for (int r = 0; r < 4; r++) {
        int er = tb * 16 + quad * 4 + r;
        if (er < deg) { m0 = fmaxf(m0, a0[r]); m1 = fmaxf(m1, a1[r]); }
      }
      m0 = fmaxf(m0, __shfl_xor(m0, 16)); m0 = fmaxf(m0, __shfl_xor(m0, 32));
      m1 = fmaxf(m1, __shfl_xor(m1, 16)); m1 = fmaxf(m1, __shfl_xor(m1, 32));
      vmax0 = fmaxf(vmax0, m0);
      vmax1 = fmaxf(vmax1, m1);
    }
    if (quad == 0) {
      int b = batch[i];
      float* pg = pooled + (size_t)b * POOLW + HF + F2;
      int u0 = (wid * 2) * 16 + n16;
      if (u0 < F2) atomicAdd(&pg[u0], fmaxf(vmax0 + b2v[0], 0.f));
      int u1 = (wid * 2 + 1) * 16 + n16;
      if (nt > 1 && u1 < F2) atomicAdd(&pg[u1], fmaxf(vmax1 + b2v[1], 0.f));
    }
  }
}

// ---------------------------------------------------------------------------
// mean-pool divide
// ---------------------------------------------------------------------------
__global__ void k_pooldiv(float* __restrict__ pooled, const int* __restrict__ cnt) {
  int t = blockIdx.x * blockDim.x + threadIdx.x;
  if (t >= BATCH * POOLW) return;
  int b = t / POOLW;
  pooled[t] /= fmaxf((float)cnt[b], 1.f);
}

// ---------------------------------------------------------------------------
// Per-graph heads: block g computes all three 2-layer MLPs -> cat[g][384]
// ---------------------------------------------------------------------------
__global__ __launch_bounds__(256) void k_heads(
    const float* __restrict__ pooled,
    const float* __restrict__ fg1_w, const float* __restrict__ fg1_b,
    const float* __restrict__ fg2_w, const float* __restrict__ fg2_b,
    const float* __restrict__ fg3_w, const float* __restrict__ fg3_b,
    const float* __restrict__ fg4_w, const float* __restrict__ fg4_b,
    const float* __restrict__ fg5_w, const float* __restrict__ fg5_b,
    const float* __restrict__ fg6_w, const float* __restrict__ fg6_b,
    float* __restrict__ cat) {
  int g = blockIdx.x, t = threadIdx.x;
  __shared__ float in[POOLW];
  __shared__ float mid[256];
  for (int idx = t; idx < POOLW; idx += 256) in[idx] = pooled[(size_t)g * POOLW + idx];
  __syncthreads();
  const float* w1s[3] = {fg1_w, fg3_w, fg5_w};
  const float* b1s[3] = {fg1_b, fg3_b, fg5_b};
  const float* w2s[3] = {fg2_w, fg4_w, fg6_w};
  const float* b2s[3] = {fg2_b, fg4_b, fg6_b};
  const int off[4] = {0, HF, HF + F2, POOLW};
  for (int br = 0; br < 3; br++) {
    int kin = off[br + 1] - off[br];
    const float* iv = &in[off[br]];
    float a = b1s[br][t];
    const float* W = w1s[br];
    for (int k = 0; k < kin; k++) a += iv[k] * W[k * 256 + t];
    mid[t] = fmaxf(a, 0.f);
    __syncthreads();
    if (t < 128) {
      float b = b2s[br][t];
      const float* W2 = w2s[br];
      for (int k = 0; k < 256; k++) b += mid[k] * W2[k * 128 + t];
      cat[(size_t)g * 384 + br * 128 + t] = fmaxf(b, 0.f);
    }
    __syncthreads();
  }
}

// ---------------------------------------------------------------------------
// Final MLP: cat[384] -> 128 -> 64 -> 1 sigmoid, block per graph
// ---------------------------------------------------------------------------
__global__ __launch_bounds__(256) void k_final(
    const float* __restrict__ cat,
    const float* __restrict__ fc1_w, const float* __restrict__ fc1_b,
    const float* __restrict__ fc2_w, const float* __restrict__ fc2_b,
    const float* __restrict__ out_w, const float* __restrict__ out_b,
    float* __restrict__ out) {
  int g = blockIdx.x, t = threadIdx.x;
  __shared__ float hin[384];
  __shared__ float h1[128];
  __shared__ float h2[64];
  for (int idx = t; idx < 384; idx += 256) hin[idx] = cat[(size_t)g * 384 + idx];
  __syncthreads();
  if (t < 128) {
    float a = fc1_b[t];
    for (int k = 0; k < 384; k++) a += hin[k] * fc1_w[k * 128 + t];
    h1[t] = fmaxf(a, 0.f);
  }
  __syncthreads();
  if (t < 64) {
    float a = fc2_b[t];
    for (int k = 0; k < 128; k++) a += h1[k] * fc2_w[k * 64 + t];
    h2[t] = fmaxf(a, 0.f);
  }
  __syncthreads();
  if (t == 0) {
    float a = out_b[0];
    for (int k = 0; k < 64; k++) a += h2[k] * out_w[k];
    out[g] = 1.f / (1.f + __expf(-a));
  }
}

// ---------------------------------------------------------------------------
extern "C" void kernel_launch(void* const* d_in, const int* in_sizes, int n_in,
                              void* d_out, int out_size, void* d_ws, size_t ws_size,
                              hipStream_t stream) {
  const float* x      = (const float*)d_in[0];
  const int*   ei     = (const int*)d_in[1];
  const int*   batch  = (const int*)d_in[2];
  const float* gat_w  = (const float*)d_in[3];
  const float* asrc   = (const float*)d_in[4];
  const float* adst   = (const float*)d_in[5];
  const float* gat_b  = (const float*)d_in[6];
  const float* gin_w1 = (const float*)d_in[7];
  const float* gin_b1 = (const float*)d_in[8];
  const float* gin_w2 = (const float*)d_in[9];
  const float* gin_b2 = (const float*)d_in[10];
  const float* ec_w1  = (const float*)d_in[11];
  const float* ec_b1  = (const float*)d_in[12];
  const float* ec_w2  = (const float*)d_in[13];
  const float* ec_b2  = (const float*)d_in[14];
  const float* fg1_w = (const float*)d_in[15]; const float* fg1_b = (const float*)d_in[16];
  const float* fg2_w = (const float*)d_in[17]; const float* fg2_b = (const float*)d_in[18];
  const float* fg3_w = (const float*)d_in[19]; const float* fg3_b = (const float*)d_in[20];
  const float* fg4_w = (const float*)d_in[21]; const float* fg4_b = (const float*)d_in[22];
  const float* fg5_w = (const float*)d_in[23]; const float* fg5_b = (const float*)d_in[24];
  const float* fg6_w = (const float*)d_in[25]; const float* fg6_b = (const float*)d_in[26];
  const float* fc1_w = (const float*)d_in[27]; const float* fc1_b = (const float*)d_in[28];
  const float* fc2_w = (const float*)d_in[29]; const float* fc2_b = (const float*)d_in[30];
  const float* out_w = (const float*)d_in[31]; const float* out_b = (const float*)d_in[32];
  float* out = (float*)d_out;

  char* ws = (char*)d_ws;
  size_t off = 0;
  auto alloc = [&](size_t bytes) -> void* {
    void* p = ws + off;
    off = (off + bytes + 255) & ~(size_t)255;
    return p;
  };
  // --- zero region (one memset): rp | cnt | pooled ---
  size_t zoff0 = off;
  int*   rp     = (int*)alloc((N_NODES + 1) * sizeof(int));
  int*   cnt    = (int*)alloc(BATCH * sizeof(int));
  float* pooled = (float*)alloc((size_t)BATCH * POOLW * sizeof(float));
  size_t zbytes = off - zoff0;
  // --- rest ---
  int*   cursor = (int*)alloc(N_NODES * sizeof(int));
  int*   bsum   = (int*)alloc(256 * sizeof(int));
  int*   colidx = (int*)alloc(N_EDGES * sizeof(int));
  float* xh     = (float*)alloc((size_t)N_NODES * HF * sizeof(float));
  float* alS    = (float*)alloc((size_t)N_NODES * 4 * sizeof(float));
  float* alD    = (float*)alloc((size_t)N_NODES * 4 * sizeof(float));
  float* Ubuf   = (float*)alloc((size_t)N_NODES * F2 * sizeof(float));
  float* Vbuf   = (float*)alloc((size_t)N_NODES * F2 * sizeof(float));
  float* cAl    = (float*)alloc(FDIM * 8 * sizeof(float));
  float* Wp     = (float*)alloc((size_t)FDIM * NPACK * sizeof(float));
  float* bpk    = (float*)alloc(NPACK * sizeof(float));
  float* cat    = (float*)alloc((size_t)BATCH * 384 * sizeof(float));
  (void)ws_size; (void)in_sizes; (void)n_in; (void)out_size;
  // GIN scratch aliases xh (xh is dead after k_gat; stream order serializes)
  float* agg = xh;                              // 50000*53
  float* h1g = xh + (size_t)N_NODES * FDIM;     // 50000*106 (total 31.8MB < 42.4MB)

  hipMemsetAsync(ws + zoff0, 0, zbytes, stream);

  k_cal<<<1, 448, 0, stream>>>(gat_w, asrc, adst, cAl);
  k_prep<<<(FDIM * NPACK + 255) / 256, 256, 0, stream>>>(gat_w, ec_w1, ec_b1, cAl, Wp, bpk);
  k_gemm<<<((N_NODES + GM - 1) / GM) * 3, 256, 0, stream>>>(x, Wp, bpk,
                                                            xh, Ubuf, Vbuf, alS, alD);
  k_hist<<<(N_EDGES + 255) / 256, 256, 0, stream>>>(ei, batch, rp, cnt);
  k_scan1<<<SCAN_BLOCKS, 256, 0, stream>>>(rp, bsum);
  k_scan2<<<1, 256, 0, stream>>>(bsum);
  k_scan3<<<SCAN_BLOCKS, 256, 0, stream>>>(bsum, rp, cursor);
  k_scatter<<<(N_EDGES + 255) / 256, 256, 0, stream>>>(ei, cursor, colidx);

  k_gat<<<(N_NODES + 3) / 4, 256, 0, stream>>>(xh, alS, alD, gat_b, rp, colidx, batch, pooled);
  k_ec<<<2048, 256, 0, stream>>>(Ubuf, Vbuf, ec_w2, ec_b2, rp, colidx, batch, pooled);
  // GIN after k_gat (agg/h1g alias xh)
  k_ginagg<<<(N_NODES + 3) / 4, 256, 0, stream>>>(x, rp, colidx, agg);
  k_gin1<<<(N_NODES + 63) / 64, 256, 0, stream>>>(agg, gin_w1, gin_b1, h1g);
  k_gin2<<<(N_NODES + 63) / 64, 256, 0, stream>>>(h1g, gin_w2, gin_b2, batch, pooled);

  k_pooldiv<<<(BATCH * POOLW + 255) / 256, 256, 0, stream>>>(pooled, cnt);

  k_heads<<<BATCH, 256, 0, stream>>>(pooled, fg1_w, fg1_b, fg2_w, fg2_b, fg3_w, fg3_b,
                                     fg4_w, fg4_b, fg5_w, fg5_b, fg6_w, fg6_b, cat);
  k_final<<<BATCH, 256, 0, stream>>>(cat, fc1_w, fc1_b, fc2_w, fc2_b, out_w, out_b, out);
}

// Round 6
// 991.650 us; speedup vs baseline: 1.6893x; 1.6122x over previous
//
#include <hip/hip_runtime.h>
#include <hip/hip_bf16.h>
#include <math.h>

#define N_NODES 50000
#define N_EDGES 800000
#define FDIM 53
#define BATCH 128
#define HF 212   /* H*F */
#define F2 106   /* 2F  */
#define POOLW 424 /* 212+106+106 */
#define NPACK 432 /* 212 + 106 + 106 + 8 */

typedef __attribute__((ext_vector_type(8))) short short8;
typedef __attribute__((ext_vector_type(4))) float f32x4;

__device__ __forceinline__ float leaky02(float x){ return x >= 0.f ? x : 0.2f * x; }

__device__ __forceinline__ short f2bf(float x) {
  unsigned u = __float_as_uint(x);
  unsigned r = (u + 0x7fffu + ((u >> 16) & 1u)) >> 16;
  return (short)r;
}
// packed pair f32x2 -> bf16x2 (v_cvt_pk_bf16_f32, RNE)
__device__ __forceinline__ unsigned pk2(float a, float b) {
  union { __hip_bfloat162 h; unsigned u; } c;
  c.h = __float22bfloat162_rn(make_float2(a, b));
  return c.u;
}

// ---------------------------------------------------------------------------
// cAl[k*8 + sd*4 + h] = sum_f gat_w[k, h*53+f] * (sd? a_dst : a_src)[h,f]
// ---------------------------------------------------------------------------
__global__ void k_cal(const float* __restrict__ gat_w, const float* __restrict__ asrc,
                      const float* __restrict__ adst, float* __restrict__ cAl) {
  int t = threadIdx.x;
  if (t >= FDIM * 8) return;
  int k = t >> 3, r = t & 7, sd = r >> 2, h = r & 3;
  const float* av = sd ? adst : asrc;
  float acc = 0.f;
  for (int f = 0; f < FDIM; ++f) acc += gat_w[k * HF + h * FDIM + f] * av[h * FDIM + f];
  cAl[t] = acc;
}

// ---------------------------------------------------------------------------
// Pack Wp[53][432] = [gat_w | W1top-W1bot | W1bot | cAl] and bias bp[432]
// ---------------------------------------------------------------------------
__global__ void k_prep(const float* __restrict__ gat_w, const float* __restrict__ ec_w1,
                       const float* __restrict__ ec_b1, const float* __restrict__ cAl,
                       float* __restrict__ Wp, float* __restrict__ bp) {
  int idx = blockIdx.x * blockDim.x + threadIdx.x;
  if (idx < FDIM * NPACK) {
    int k = idx / NPACK, j = idx % NPACK;
    float v;
    if (j < HF)            v = gat_w[k * HF + j];
    else if (j < HF + F2)  v = ec_w1[k * F2 + (j - HF)] - ec_w1[(FDIM + k) * F2 + (j - HF)];
    else if (j < POOLW)    v = ec_w1[(FDIM + k) * F2 + (j - HF - F2)];
    else                   v = cAl[k * 8 + (j - POOLW)];
    Wp[idx] = v;
  }
  if (idx < NPACK) {
    bp[idx] = (idx >= HF && idx < HF + F2) ? ec_b1[idx - HF] : 0.f;
  }
}

// ---------------------------------------------------------------------------
// Node-linear as tiled fp32 GEMM: x[50000x53] @ Wp[53x432] + bp.
// ---------------------------------------------------------------------------
#define GM 64
#define GN 144
#define APAD 57
__global__ __launch_bounds__(256) void k_gemm(
    const float* __restrict__ x, const float* __restrict__ Wp, const float* __restrict__ bp,
    float* __restrict__ xh, float* __restrict__ U, float* __restrict__ V,
    float* __restrict__ alS, float* __restrict__ alD) {
  __shared__ float As[GM * APAD];
  __shared__ float Ws[FDIM * GN];
  int mb = blockIdx.x / 3, nc = blockIdx.x % 3;
  int m0 = mb * GM, n0 = nc * GN;
  int t = threadIdx.x;
  for (int idx = t; idx < GM * FDIM; idx += 256) {
    int m = idx / FDIM, k = idx % FDIM;
    int gm = m0 + m;
    As[m * APAD + k] = (gm < N_NODES) ? x[(size_t)gm * FDIM + k] : 0.f;
  }
  for (int idx = t; idx < FDIM * GN; idx += 256) {
    int k = idx / GN, n = idx % GN;
    Ws[idx] = Wp[k * NPACK + n0 + n];
  }
  __syncthreads();
  int tx = t & 15, ty = t >> 4;
  int ms = tx * 4, ns = ty * 9;
  float acc[4][9];
#pragma unroll
  for (int i = 0; i < 4; i++)
#pragma unroll
    for (int j = 0; j < 9; j++) acc[i][j] = 0.f;
  for (int k = 0; k < FDIM; k++) {
    float a0 = As[(ms + 0) * APAD + k];
    float a1 = As[(ms + 1) * APAD + k];
    float a2 = As[(ms + 2) * APAD + k];
    float a3 = As[(ms + 3) * APAD + k];
    float b[9];
#pragma unroll
    for (int j = 0; j < 9; j++) b[j] = Ws[k * GN + ns + j];
#pragma unroll
    for (int j = 0; j < 9; j++) {
      acc[0][j] += a0 * b[j];
      acc[1][j] += a1 * b[j];
      acc[2][j] += a2 * b[j];
      acc[3][j] += a3 * b[j];
    }
  }
  float bj[9];
#pragma unroll
  for (int j = 0; j < 9; j++) bj[j] = bp[n0 + ns + j];
#pragma unroll
  for (int i = 0; i < 4; i++) {
    int gm = m0 + ms + i;
    if (gm >= N_NODES) break;
#pragma unroll
    for (int j = 0; j < 9; j++) {
      int g = n0 + ns + j;
      float v = acc[i][j] + bj[j];
      if (g < HF)            xh[(size_t)gm * HF + g] = v;
      else if (g < HF + F2)  U[(size_t)gm * F2 + (g - HF)] = v;
      else if (g < POOLW)    V[(size_t)gm * F2 + (g - HF - F2)] = v;
      else if (g < POOLW + 4) alS[gm * 4 + (g - POOLW)] = v;
      else                   alD[gm * 4 + (g - POOLW - 4)] = v;
    }
  }
}

// ---------------------------------------------------------------------------
// CSR build: histogram, 3-phase multi-block scan, scatter
// ---------------------------------------------------------------------------
#define SCAN_BLOCKS ((N_NODES + 255) / 256)

__global__ void k_hist(const int* __restrict__ ei, const int* __restrict__ batch,
                       int* __restrict__ rp, int* __restrict__ cnt) {
  int t = blockIdx.x * blockDim.x + threadIdx.x;
  if (t < N_EDGES) atomicAdd(&rp[ei[N_EDGES + t]], 1);
  if (t < N_NODES) atomicAdd(&cnt[batch[t]], 1);
}

__global__ __launch_bounds__(256) void k_scan1(int* __restrict__ rp, int* __restrict__ bsum) {
  __shared__ int buf[256];
  int tid = threadIdx.x;
  int idx = blockIdx.x * 256 + tid;
  int v = (idx < N_NODES) ? rp[idx] : 0;
  buf[tid] = v;
  __syncthreads();
  for (int off = 1; off < 256; off <<= 1) {
    int t2 = (tid >= off) ? buf[tid - off] : 0;
    __syncthreads();
    buf[tid] += t2;
    __syncthreads();
  }
  if (idx < N_NODES) rp[idx] = buf[tid] - v;
  if (tid == 255) bsum[blockIdx.x] = buf[255];
}

__global__ __launch_bounds__(256) void k_scan2(int* __restrict__ bsum) {
  __shared__ int buf[256];
  int tid = threadIdx.x;
  int v = (tid < SCAN_BLOCKS) ? bsum[tid] : 0;
  buf[tid] = v;
  __syncthreads();
  for (int off = 1; off < 256; off <<= 1) {
    int t2 = (tid >= off) ? buf[tid - off] : 0;
    __syncthreads();
    buf[tid] += t2;
    __syncthreads();
  }
  if (tid < SCAN_BLOCKS) bsum[tid] = buf[tid] - v;
}

__global__ __launch_bounds__(256) void k_scan3(const int* __restrict__ bsum,
                                               int* __restrict__ rp, int* __restrict__ cursor) {
  int idx = blockIdx.x * 256 + threadIdx.x;
  if (idx < N_NODES) {
    int o = rp[idx] + bsum[blockIdx.x];
    rp[idx] = o;
    cursor[idx] = o;
  }
  if (idx == 0) rp[N_NODES] = N_EDGES;
}

__global__ void k_scatter(const int* __restrict__ ei, int* __restrict__ cursor,
                          int* __restrict__ colidx) {
  int e = blockIdx.x * blockDim.x + threadIdx.x;
  if (e >= N_EDGES) return;
  int d = ei[N_EDGES + e];
  int pos = atomicAdd(&cursor[d], 1);
  colidx[pos] = ei[e];
}

// ---------------------------------------------------------------------------
// GAT: wave per node, block owns GCH contiguous nodes (sorted batch =>
// <=2 graphs per block). Per-lane register pool accumulation, flush on
// batch change: 10.6M global atomics -> ~40K.
// ---------------------------------------------------------------------------
#define GCH 40
__global__ __launch_bounds__(256) void k_gat(
    const float* __restrict__ xh, const float* __restrict__ alS, const float* __restrict__ alD,
    const float* __restrict__ bias, const int* __restrict__ rp, const int* __restrict__ colidx,
    const int* __restrict__ batch, float* __restrict__ pooled) {
  int wid = threadIdx.x >> 6, lane = threadIdx.x & 63;
  int f0 = lane, f1 = lane + 64, f2 = lane + 128, f3 = lane + 192;
  bool v3 = (f3 < HF);
  bool h0a = f0 < FDIM;
  bool h1a = f1 < 2 * FDIM;
  bool h2a = f2 < 3 * FDIM;
  float bi0 = bias[f0], bi1 = bias[f1], bi2 = bias[f2], bi3 = bias[v3 ? f3 : 0];
  float r0 = 0.f, r1 = 0.f, r2 = 0.f, r3 = 0.f;
  int curb = -1;
  int i0 = blockIdx.x * GCH;
  int iend = min(i0 + GCH, N_NODES);
  for (int i = i0 + wid; i < iend; i += 4) {
    int base = rp[i], deg = rp[i + 1] - base;
    float aldi[4], esf[4];
#pragma unroll
    for (int h = 0; h < 4; h++) {
      aldi[h] = alD[i * 4 + h];
      esf[h] = leaky02(alS[i * 4 + h] + aldi[h]);
    }
    float mx[4] = {-1e30f, -1e30f, -1e30f, -1e30f};
    for (int c = lane; c < deg; c += 64) {
      int s = colidx[base + c];
#pragma unroll
      for (int h = 0; h < 4; h++) mx[h] = fmaxf(mx[h], leaky02(alS[s * 4 + h] + aldi[h]));
    }
#pragma unroll
    for (int off = 32; off >= 1; off >>= 1)
#pragma unroll
      for (int h = 0; h < 4; h++) mx[h] = fmaxf(mx[h], __shfl_xor(mx[h], off));
    float m[4], exs[4];
#pragma unroll
    for (int h = 0; h < 4; h++) { m[h] = fmaxf(mx[h], esf[h]); exs[h] = __expf(esf[h] - m[h]); }

    const float* xhi = xh + (size_t)i * HF;
    float acc0 = (h0a ? exs[0] : exs[1]) * xhi[f0];
    float acc1 = (h1a ? exs[1] : exs[2]) * xhi[f1];
    float acc2 = (h2a ? exs[2] : exs[3]) * xhi[f2];
    float acc3 = v3 ? exs[3] * xhi[f3] : 0.f;
    float zl[4] = {0.f, 0.f, 0.f, 0.f};

    for (int c0 = 0; c0 < deg; c0 += 64) {
      int cn = min(64, deg - c0);
      int s = 0;
      float ex0 = 0.f, ex1 = 0.f, ex2 = 0.f, ex3 = 0.f;
      if (lane < cn) {
        s = colidx[base + c0 + lane];
        ex0 = __expf(leaky02(alS[s * 4 + 0] + aldi[0]) - m[0]);
        ex1 = __expf(leaky02(alS[s * 4 + 1] + aldi[1]) - m[1]);
        ex2 = __expf(leaky02(alS[s * 4 + 2] + aldi[2]) - m[2]);
        ex3 = __expf(leaky02(alS[s * 4 + 3] + aldi[3]) - m[3]);
        zl[0] += ex0; zl[1] += ex1; zl[2] += ex2; zl[3] += ex3;
      }
      for (int jj = 0; jj < cn; jj++) {
        int sj = __shfl(s, jj);
        float a0 = __shfl(ex0, jj), a1 = __shfl(ex1, jj);
        float a2 = __shfl(ex2, jj), a3 = __shfl(ex3, jj);
        const float* xr = xh + (size_t)sj * HF;
        acc0 += (h0a ? a0 : a1) * xr[f0];
        acc1 += (h1a ? a1 : a2) * xr[f1];
        acc2 += (h2a ? a2 : a3) * xr[f2];
        if (v3) acc3 += a3 * xr[f3];
      }
    }
#pragma unroll
    for (int off = 32; off >= 1; off >>= 1)
#pragma unroll
      for (int h = 0; h < 4; h++) zl[h] += __shfl_xor(zl[h], off);
    float z[4];
#pragma unroll
    for (int h = 0; h < 4; h++) z[h] = zl[h] + exs[h] + 1e-16f;

    float o0 = fmaxf(acc0 / (h0a ? z[0] : z[1]) + bi0, 0.f);
    float o1 = fmaxf(acc1 / (h1a ? z[1] : z[2]) + bi1, 0.f);
    float o2 = fmaxf(acc2 / (h2a ? z[2] : z[3]) + bi2, 0.f);
    float o3 = v3 ? fmaxf(acc3 / z[3] + bi3, 0.f) : 0.f;
    int b = batch[i];
    if (b != curb) {
      if (curb >= 0) {
        float* pg = pooled + (size_t)curb * POOLW;
        atomicAdd(&pg[f0], r0);
        atomicAdd(&pg[f1], r1);
        atomicAdd(&pg[f2], r2);
        if (v3) atomicAdd(&pg[f3], r3);
      }
      curb = b; r0 = o0; r1 = o1; r2 = o2; r3 = o3;
    } else {
      r0 += o0; r1 += o1; r2 += o2; r3 += o3;
    }
  }
  if (curb >= 0) {
    float* pg = pooled + (size_t)curb * POOLW;
    atomicAdd(&pg[f0], r0);
    atomicAdd(&pg[f1], r1);
    atomicAdd(&pg[f2], r2);
    if (v3) atomicAdd(&pg[f3], r3);
  }
}

// ---------------------------------------------------------------------------
// GIN split: (1) gather-sum agg = x + sum_neighbors x  -> agg[50k x 53]
// ---------------------------------------------------------------------------
__global__ __launch_bounds__(256) void k_ginagg(
    const float* __restrict__ x, const int* __restrict__ rp, const int* __restrict__ colidx,
    float* __restrict__ agg) {
  int wid = threadIdx.x >> 6, lane = threadIdx.x & 63;
  int i = blockIdx.x * 4 + wid;
  if (i >= N_NODES) return;
  int base = rp[i], deg = rp[i + 1] - base;
  float hk = (lane < FDIM) ? x[(size_t)i * FDIM + lane] : 0.f;
  int c = 0;
  for (; c + 4 <= deg; c += 4) {
    int s0 = colidx[base + c + 0];
    int s1 = colidx[base + c + 1];
    int s2 = colidx[base + c + 2];
    int s3 = colidx[base + c + 3];
    if (lane < FDIM) {
      float v0 = x[(size_t)s0 * FDIM + lane];
      float v1 = x[(size_t)s1 * FDIM + lane];
      float v2 = x[(size_t)s2 * FDIM + lane];
      float v3 = x[(size_t)s3 * FDIM + lane];
      hk += (v0 + v1) + (v2 + v3);
    }
  }
  for (; c < deg; c++) {
    int s = colidx[base + c];
    if (lane < FDIM) hk += x[(size_t)s * FDIM + lane];
  }
  if (lane < FDIM) agg[(size_t)i * FDIM + lane] = hk;
}

// ---------------------------------------------------------------------------
// GIN (2): h1g = relu(agg @ w1 + b1), tiled fp32 GEMM 64x106, K=53
// ---------------------------------------------------------------------------
__global__ __launch_bounds__(256) void k_gin1(
    const float* __restrict__ agg, const float* __restrict__ w1, const float* __restrict__ b1,
    float* __restrict__ h1g) {
  __shared__ float As[64 * APAD];
  __shared__ float Ws[FDIM * 112];
  int m0 = blockIdx.x * 64;
  int t = threadIdx.x;
  for (int idx = t; idx < 64 * FDIM; idx += 256) {
    int m = idx / FDIM, k = idx % FDIM;
    int gm = m0 + m;
    As[m * APAD + k] = (gm < N_NODES) ? agg[(size_t)gm * FDIM + k] : 0.f;
  }
  for (int idx = t; idx < FDIM * 112; idx += 256) {
    int k = idx / 112, n = idx % 112;
    Ws[idx] = (n < F2) ? w1[k * F2 + n] : 0.f;
  }
  __syncthreads();
  int tx = t & 15, ty = t >> 4;
  int ms = tx * 4, ns = ty * 7;
  float acc[4][7];
#pragma unroll
  for (int i = 0; i < 4; i++)
#pragma unroll
    for (int j = 0; j < 7; j++) acc[i][j] = 0.f;
  for (int k = 0; k < FDIM; k++) {
    float a0 = As[(ms + 0) * APAD + k];
    float a1 = As[(ms + 1) * APAD + k];
    float a2 = As[(ms + 2) * APAD + k];
    float a3 = As[(ms + 3) * APAD + k];
    float b[7];
#pragma unroll
    for (int j = 0; j < 7; j++) b[j] = Ws[k * 112 + ns + j];
#pragma unroll
    for (int j = 0; j < 7; j++) {
      acc[0][j] += a0 * b[j];
      acc[1][j] += a1 * b[j];
      acc[2][j] += a2 * b[j];
      acc[3][j] += a3 * b[j];
    }
  }
#pragma unroll
  for (int i = 0; i < 4; i++) {
    int gm = m0 + ms + i;
    if (gm >= N_NODES) break;
#pragma unroll
    for (int j = 0; j < 7; j++) {
      int n = ns + j;
      if (n < F2) h1g[(size_t)gm * F2 + n] = fmaxf(acc[i][j] + b1[n], 0.f);
    }
  }
}

// ---------------------------------------------------------------------------
// GIN (3): h2 = relu(h1g @ w2 + b2) + pooling via per-thread register accum
// -> LDS psum[4][112] -> few distinct-address global atomics per block.
// ---------------------------------------------------------------------------
#define A2PAD 111
__global__ __launch_bounds__(256) void k_gin2(
    const float* __restrict__ h1g, const float* __restrict__ w2, const float* __restrict__ b2,
    const int* __restrict__ batch, float* __restrict__ pooled) {
  __shared__ float As[64 * A2PAD];
  __shared__ float Ws[F2 * 112];
  __shared__ float psum[4 * 112];
  int m0 = blockIdx.x * 64;
  int t = threadIdx.x;
  for (int idx = t; idx < 4 * 112; idx += 256) psum[idx] = 0.f;
  for (int idx = t; idx < 64 * F2; idx += 256) {
    int m = idx / F2, k = idx % F2;
    int gm = m0 + m;
    As[m * A2PAD + k] = (gm < N_NODES) ? h1g[(size_t)gm * F2 + k] : 0.f;
  }
  for (int idx = t; idx < F2 * 112; idx += 256) {
    int k = idx / 112, n = idx % 112;
    Ws[idx] = (n < F2) ? w2[k * F2 + n] : 0.f;
  }
  __syncthreads();
  int tx = t & 15, ty = t >> 4;
  int ms = tx * 4, ns = ty * 7;
  float acc[4][7];
#pragma unroll
  for (int i = 0; i < 4; i++)
#pragma unroll
    for (int j = 0; j < 7; j++) acc[i][j] = 0.f;
  for (int k = 0; k < F2; k++) {
    float a0 = As[(ms + 0) * A2PAD + k];
    float a1 = As[(ms + 1) * A2PAD + k];
    float a2 = As[(ms + 2) * A2PAD + k];
    float a3 = As[(ms + 3) * A2PAD + k];
    float b[7];
#pragma unroll
    for (int j = 0; j < 7; j++) b[j] = Ws[k * 112 + ns + j];
#pragma unroll
    for (int j = 0; j < 7; j++) {
      acc[0][j] += a0 * b[j];
      acc[1][j] += a1 * b[j];
      acc[2][j] += a2 * b[j];
      acc[3][j] += a3 * b[j];
    }
  }
  // epilogue: relu(acc + b2), per-thread register pool accum over the 4 rows
  float b2n[7];
#pragma unroll
  for (int j = 0; j < 7; j++) {
    int n = ns + j;
    b2n[j] = (n < F2) ? b2[n] : 0.f;
  }
  int bmin = batch[m0];
  float pj[7];
#pragma unroll
  for (int j = 0; j < 7; j++) pj[j] = 0.f;
  int curb = -1;
#pragma unroll
  for (int i = 0; i < 4; i++) {
    int gm = m0 + ms + i;
    if (gm >= N_NODES) break;
    int b = batch[gm];
    if (b != curb) {
      if (curb >= 0) {
        int slot = curb - bmin;
        if (slot >= 0 && slot < 4) {
#pragma unroll
          for (int j = 0; j < 7; j++)
            if (ns + j < F2) atomicAdd(&psum[slot * 112 + ns + j], pj[j]);
        } else {
          float* pg = pooled + (size_t)curb * POOLW + HF;
#pragma unroll
          for (int j = 0; j < 7; j++)
            if (ns + j < F2) atomicAdd(&pg[ns + j], pj[j]);
        }
      }
      curb = b;
#pragma unroll
      for (int j = 0; j < 7; j++)
        pj[j] = (ns + j < F2) ? fmaxf(acc[i][j] + b2n[j], 0.f) : 0.f;
    } else {
#pragma unroll
      for (int j = 0; j < 7; j++)
        if (ns + j < F2) pj[j] += fmaxf(acc[i][j] + b2n[j], 0.f);
    }
  }
  if (curb >= 0) {
    int slot = curb - bmin;
    if (slot >= 0 && slot < 4) {
#pragma unroll
      for (int j = 0; j < 7; j++)
        if (ns + j < F2) atomicAdd(&psum[slot * 112 + ns + j], pj[j]);
    } else {
      float* pg = pooled + (size_t)curb * POOLW + HF;
#pragma unroll
      for (int j = 0; j < 7; j++)
        if (ns + j < F2) atomicAdd(&pg[ns + j], pj[j]);
    }
  }
  __syncthreads();
  for (int idx = t; idx < 4 * 112; idx += 256) {
    int slot = idx / 112, n = idx % 112;
    float v = psum[idx];
    int b = bmin + slot;
    if (n < F2 && b < BATCH && v != 0.f)
      atomicAdd(&pooled[(size_t)b * POOLW + HF + n], v);
  }
}

// ---------------------------------------------------------------------------
// EdgeConv v6: LDS-staged single-pass bf16 MFMA; block owns ECH contiguous
// nodes; register pool accumulation, flush on batch change.
// ---------------------------------------------------------------------------
#define ECH 25
__global__ __launch_bounds__(256) void k_ec(
    const float* __restrict__ U, const float* __restrict__ V,
    const float* __restrict__ w2, const float* __restrict__ b2,
    const int* __restrict__ rp, const int* __restrict__ colidx,
    const int* __restrict__ batch, float* __restrict__ pooled) {
  const int t = threadIdx.x;
  const int lane = t & 63, wid = t >> 6;
  const int n16 = lane & 15, quad = lane >> 4;
  const int nt = (wid == 3) ? 1 : 2;   // u-tile 7 is all-pad

  // B fragments (bf16), once per block
  short8 Bh[2][4];
  for (int tt = 0; tt < 2; tt++) {
    int ucol = (wid * 2 + tt) * 16 + n16;
    for (int kc = 0; kc < 4; kc++) {
      short8 vh;
#pragma unroll
      for (int jv = 0; jv < 8; jv++) {
        int kk = kc * 32 + quad * 8 + jv;
        float w = (ucol < F2 && kk < F2) ? w2[kk * F2 + ucol] : 0.f;
        vh[jv] = f2bf(w);
      }
      Bh[tt][kc] = vh;
    }
  }
  float b2v[2];
#pragma unroll
  for (int tt = 0; tt < 2; tt++) {
    int u = (wid * 2 + tt) * 16 + n16;
    b2v[tt] = (u < F2) ? b2[u] : 0.f;
  }

  __shared__ short hs[16 * 16 * 8];   // [kg][es][8 shorts] = 4 KB
  union SU { short8 s; unsigned u[4]; };
  const int es = t & 15, kg = t >> 4;  // staging roles
  const int k0 = kg * 8;

  float sm0 = 0.f, sm1 = 0.f;
  int curb = -1;
  const int u0 = (wid * 2) * 16 + n16;
  const int u1 = (wid * 2 + 1) * 16 + n16;

  int i0 = blockIdx.x * ECH;
  int iend = min(i0 + ECH, N_NODES);
  for (int i = i0; i < iend; i++) {
    int base = rp[i], deg = rp[i + 1] - base;
    if (deg == 0) continue;   // empty segment -> 0 after relu -> no contribution
    float Uv[8];
    {
      const float2* up = (const float2*)(U + (size_t)i * F2 + k0);
#pragma unroll
      for (int p = 0; p < 4; p++) { float2 v = up[p]; Uv[2*p] = v.x; Uv[2*p+1] = v.y; }
    }
    float vmax0 = -1e30f, vmax1 = -1e30f;
    int ntile = (deg + 15) >> 4;
    for (int tb = 0; tb < ntile; tb++) {
      int eg = tb * 16 + es;
      int s = (eg < deg) ? colidx[base + eg] : 0;
      const float2* vp = (const float2*)(V + (size_t)s * F2 + k0);
      SU w;
#pragma unroll
      for (int p = 0; p < 4; p++) {
        float2 v = vp[p];
        bool pv = (k0 + 2 * p) < F2;
        float h0 = pv ? fmaxf(Uv[2*p] + v.x, 0.f) : 0.f;
        float h1 = pv ? fmaxf(Uv[2*p+1] + v.y, 0.f) : 0.f;
        w.u[p] = pk2(h0, h1);
      }
      __syncthreads();                  // WAR: prev tile's frag reads done
      *(short8*)&hs[(kg * 16 + es) * 8] = w.s;
      __syncthreads();                  // RAW
      f32x4 a0 = {0.f, 0.f, 0.f, 0.f}, a1 = {0.f, 0.f, 0.f, 0.f};
#pragma unroll
      for (int kc = 0; kc < 4; kc++) {
        short8 af = *(const short8*)&hs[((kc * 4 + quad) * 16 + n16) * 8];
        a0 = __builtin_amdgcn_mfma_f32_16x16x32_bf16(af, Bh[0][kc], a0, 0, 0, 0);
        if (nt > 1)
          a1 = __builtin_amdgcn_mfma_f32_16x16x32_bf16(af, Bh[1][kc], a1, 0, 0, 0);
      }
      float m0 = -1e30f, m1 = -1e30f;
#pragma unroll
      for (int r = 0; r < 4; r++) {
        int er = tb * 16 + quad * 4 + r;
        if (er < deg) { m0 = fmaxf(m0, a0[r]); m1 = fmaxf(m1, a1[r]); }
      }
      m0 = fmaxf(m0, __shfl_xor(m0, 16)); m0 = fmaxf(m0, __shfl_xor(m0, 32));
      m1 = fmaxf(m1, __shfl_xor(m1, 16)); m1 = fmaxf(m1, __shfl_xor(m1, 32));
      vmax0 = fmaxf(vmax0, m0);
      vmax1 = fmaxf(vmax1, m1);
    }
    float o0 = fmaxf(vmax0 + b2v[0], 0.f);
    float o1 = fmaxf(vmax1 + b2v[1], 0.f);
    int b = batch[i];
    if (b != curb) {
      if (curb >= 0 && quad == 0) {
        float* pg = pooled + (size_t)curb * POOLW + HF + F2;
        if (u0 < F2) atomicAdd(&pg[u0], sm0);
        if (nt > 1 && u1 < F2) atomicAdd(&pg[u1], sm1);
      }
      curb = b; sm0 = o0; sm1 = o1;
    } else {
      sm0 += o0; sm1 += o1;
    }
  }
  if (curb >= 0 && quad == 0) {
    float* pg = pooled + (size_t)curb * POOLW + HF + F2;
    if (u0 < F2) atomicAdd(&pg[u0], sm0);
    if (nt > 1 && u1 < F2) atomicAdd(&pg[u1], sm1);
  }
}

// ---------------------------------------------------------------------------
// mean-pool divide
// ---------------------------------------------------------------------------
__global__ void k_pooldiv(float* __restrict__ pooled, const int* __restrict__ cnt) {
  int t = blockIdx.x * blockDim.x + threadIdx.x;
  if (t >= BATCH * POOLW) return;
  int b = t / POOLW;
  pooled[t] /= fmaxf((float)cnt[b], 1.f);
}

// ---------------------------------------------------------------------------
// Per-graph heads: block g computes all three 2-layer MLPs -> cat[g][384]
// ---------------------------------------------------------------------------
__global__ __launch_bounds__(256) void k_heads(
    const float* __restrict__ pooled,
    const float* __restrict__ fg1_w, const float* __restrict__ fg1_b,
    const float* __restrict__ fg2_w, const float* __restrict__ fg2_b,
    const float* __restrict__ fg3_w, const float* __restrict__ fg3_b,
    const float* __restrict__ fg4_w, const float* __restrict__ fg4_b,
    const float* __restrict__ fg5_w, const float* __restrict__ fg5_b,
    const float* __restrict__ fg6_w, const float* __restrict__ fg6_b,
    float* __restrict__ cat) {
  int g = blockIdx.x, t = threadIdx.x;
  __shared__ float in[POOLW];
  __shared__ float mid[256];
  for (int idx = t; idx < POOLW; idx += 256) in[idx] = pooled[(size_t)g * POOLW + idx];
  __syncthreads();
  const float* w1s[3] = {fg1_w, fg3_w, fg5_w};
  const float* b1s[3] = {fg1_b, fg3_b, fg5_b};
  const float* w2s[3] = {fg2_w, fg4_w, fg6_w};
  const float* b2s[3] = {fg2_b, fg4_b, fg6_b};
  const int off[4] = {0, HF, HF + F2, POOLW};
  for (int br = 0; br < 3; br++) {
    int kin = off[br + 1] - off[br];
    const float* iv = &in[off[br]];
    float a = b1s[br][t];
    const float* W = w1s[br];
    for (int k = 0; k < kin; k++) a += iv[k] * W[k * 256 + t];
    mid[t] = fmaxf(a, 0.f);
    __syncthreads();
    if (t < 128) {
      float b = b2s[br][t];
      const float* W2 = w2s[br];
      for (int k = 0; k < 256; k++) b += mid[k] * W2[k * 128 + t];
      cat[(size_t)g * 384 + br * 128 + t] = fmaxf(b, 0.f);
    }
    __syncthreads();
  }
}

// ---------------------------------------------------------------------------
// Final MLP: cat[384] -> 128 -> 64 -> 1 sigmoid, block per graph
// ---------------------------------------------------------------------------
__global__ __launch_bounds__(256) void k_final(
    const float* __restrict__ cat,
    const float* __restrict__ fc1_w, const float* __restrict__ fc1_b,
    const float* __restrict__ fc2_w, const float* __restrict__ fc2_b,
    const float* __restrict__ out_w, const float* __restrict__ out_b,
    float* __restrict__ out) {
  int g = blockIdx.x, t = threadIdx.x;
  __shared__ float hin[384];
  __shared__ float h1[128];
  __shared__ float h2[64];
  for (int idx = t; idx < 384; idx += 256) hin[idx] = cat[(size_t)g * 384 + idx];
  __syncthreads();
  if (t < 128) {
    float a = fc1_b[t];
    for (int k = 0; k < 384; k++) a += hin[k] * fc1_w[k * 128 + t];
    h1[t] = fmaxf(a, 0.f);
  }
  __syncthreads();
  if (t < 64) {
    float a = fc2_b[t];
    for (int k = 0; k < 128; k++) a += h1[k] * fc2_w[k * 64 + t];
    h2[t] = fmaxf(a, 0.f);
  }
  __syncthreads();
  if (t == 0) {
    float a = out_b[0];
    for (int k = 0; k < 64; k++) a += h2[k] * out_w[k];
    out[g] = 1.f / (1.f + __expf(-a));
  }
}

// ---------------------------------------------------------------------------
extern "C" void kernel_launch(void* const* d_in, const int* in_sizes, int n_in,
                              void* d_out, int out_size, void* d_ws, size_t ws_size,
                              hipStream_t stream) {
  const float* x      = (const float*)d_in[0];
  const int*   ei     = (const int*)d_in[1];
  const int*   batch  = (const int*)d_in[2];
  const float* gat_w  = (const float*)d_in[3];
  const float* asrc   = (const float*)d_in[4];
  const float* adst   = (const float*)d_in[5];
  const float* gat_b  = (const float*)d_in[6];
  const float* gin_w1 = (const float*)d_in[7];
  const float* gin_b1 = (const float*)d_in[8];
  const float* gin_w2 = (const float*)d_in[9];
  const float* gin_b2 = (const float*)d_in[10];
  const float* ec_w1  = (const float*)d_in[11];
  const float* ec_b1  = (const float*)d_in[12];
  const float* ec_w2  = (const float*)d_in[13];
  const float* ec_b2  = (const float*)d_in[14];
  const float* fg1_w = (const float*)d_in[15]; const float* fg1_b = (const float*)d_in[16];
  const float* fg2_w = (const float*)d_in[17]; const float* fg2_b = (const float*)d_in[18];
  const float* fg3_w = (const float*)d_in[19]; const float* fg3_b = (const float*)d_in[20];
  const float* fg4_w = (const float*)d_in[21]; const float* fg4_b = (const float*)d_in[22];
  const float* fg5_w = (const float*)d_in[23]; const float* fg5_b = (const float*)d_in[24];
  const float* fg6_w = (const float*)d_in[25]; const float* fg6_b = (const float*)d_in[26];
  const float* fc1_w = (const float*)d_in[27]; const float* fc1_b = (const float*)d_in[28];
  const float* fc2_w = (const float*)d_in[29]; const float* fc2_b = (const float*)d_in[30];
  const float* out_w = (const float*)d_in[31]; const float* out_b = (const float*)d_in[32];
  float* out = (float*)d_out;

  char* ws = (char*)d_ws;
  size_t off = 0;
  auto alloc = [&](size_t bytes) -> void* {
    void* p = ws + off;
    off = (off + bytes + 255) & ~(size_t)255;
    return p;
  };
  // --- zero region (one memset): rp | cnt | pooled ---
  size_t zoff0 = off;
  int*   rp     = (int*)alloc((N_NODES + 1) * sizeof(int));
  int*   cnt    = (int*)alloc(BATCH * sizeof(int));
  float* pooled = (float*)alloc((size_t)BATCH * POOLW * sizeof(float));
  size_t zbytes = off - zoff0;
  // --- rest ---
  int*   cursor = (int*)alloc(N_NODES * sizeof(int));
  int*   bsum   = (int*)alloc(256 * sizeof(int));
  int*   colidx = (int*)alloc(N_EDGES * sizeof(int));
  float* xh     = (float*)alloc((size_t)N_NODES * HF * sizeof(float));
  float* alS    = (float*)alloc((size_t)N_NODES * 4 * sizeof(float));
  float* alD    = (float*)alloc((size_t)N_NODES * 4 * sizeof(float));
  float* Ubuf   = (float*)alloc((size_t)N_NODES * F2 * sizeof(float));
  float* Vbuf   = (float*)alloc((size_t)N_NODES * F2 * sizeof(float));
  float* cAl    = (float*)alloc(FDIM * 8 * sizeof(float));
  float* Wp     = (float*)alloc((size_t)FDIM * NPACK * sizeof(float));
  float* bpk    = (float*)alloc(NPACK * sizeof(float));
  float* cat    = (float*)alloc((size_t)BATCH * 384 * sizeof(float));
  (void)ws_size; (void)in_sizes; (void)n_in; (void)out_size;
  // GIN scratch aliases xh (xh is dead after k_gat; stream order serializes)
  float* agg = xh;                              // 50000*53
  float* h1g = xh + (size_t)N_NODES * FDIM;     // 50000*106

  hipMemsetAsync(ws + zoff0, 0, zbytes, stream);

  k_cal<<<1, 448, 0, stream>>>(gat_w, asrc, adst, cAl);
  k_prep<<<(FDIM * NPACK + 255) / 256, 256, 0, stream>>>(gat_w, ec_w1, ec_b1, cAl, Wp, bpk);
  k_gemm<<<((N_NODES + GM - 1) / GM) * 3, 256, 0, stream>>>(x, Wp, bpk,
                                                            xh, Ubuf, Vbuf, alS, alD);
  k_hist<<<(N_EDGES + 255) / 256, 256, 0, stream>>>(ei, batch, rp, cnt);
  k_scan1<<<SCAN_BLOCKS, 256, 0, stream>>>(rp, bsum);
  k_scan2<<<1, 256, 0, stream>>>(bsum);
  k_scan3<<<SCAN_BLOCKS, 256, 0, stream>>>(bsum, rp, cursor);
  k_scatter<<<(N_EDGES + 255) / 256, 256, 0, stream>>>(ei, cursor, colidx);

  k_gat<<<(N_NODES + GCH - 1) / GCH, 256, 0, stream>>>(xh, alS, alD, gat_b, rp, colidx, batch, pooled);
  k_ec<<<(N_NODES + ECH - 1) / ECH, 256, 0, stream>>>(Ubuf, Vbuf, ec_w2, ec_b2, rp, colidx, batch, pooled);
  // GIN after k_gat (agg/h1g alias xh)
  k_ginagg<<<(N_NODES + 3) / 4, 256, 0, stream>>>(x, rp, colidx, agg);
  k_gin1<<<(N_NODES + 63) / 64, 256, 0, stream>>>(agg, gin_w1, gin_b1, h1g);
  k_gin2<<<(N_NODES + 63) / 64, 256, 0, stream>>>(h1g, gin_w2, gin_b2, batch, pooled);

  k_pooldiv<<<(BATCH * POOLW + 255) / 256, 256, 0, stream>>>(pooled, cnt);

  k_heads<<<BATCH, 256, 0, stream>>>(pooled, fg1_w, fg1_b, fg2_w, fg2_b, fg3_w, fg3_b,
                                     fg4_w, fg4_b, fg5_w, fg5_b, fg6_w, fg6_b, cat);
  k_final<<<BATCH, 256, 0, stream>>>(cat, fc1_w, fc1_b, fc2_w, fc2_b, out_w, out_b, out);
}

// Round 7
// 886.657 us; speedup vs baseline: 1.8893x; 1.1184x over previous
//
#include <hip/hip_runtime.h>
#include <hip/hip_bf16.h>
#include <math.h>

#define N_NODES 50000
#define N_EDGES 800000
#define FDIM 53
#define BATCH 128
#define HF 212   /* H*F */
#define F2 106   /* 2F  */
#define POOLW 424 /* 212+106+106 */
#define NPACK 432 /* 212 + 106 + 106 + 8 */

typedef __attribute__((ext_vector_type(8))) short short8;
typedef __attribute__((ext_vector_type(4))) float f32x4;

__device__ __forceinline__ float leaky02(float x){ return x >= 0.f ? x : 0.2f * x; }

__device__ __forceinline__ short f2bf(float x) {
  unsigned u = __float_as_uint(x);
  unsigned r = (u + 0x7fffu + ((u >> 16) & 1u)) >> 16;
  return (short)r;
}
__device__ __forceinline__ float bf2f(short b) {
  return __uint_as_float(((unsigned)(unsigned short)b) << 16);
}
// packed pair f32x2 -> bf16x2 (v_cvt_pk_bf16_f32, RNE)
__device__ __forceinline__ unsigned pk2(float a, float b) {
  union { __hip_bfloat162 h; unsigned u; } c;
  c.h = __float22bfloat162_rn(make_float2(a, b));
  return c.u;
}
// LDS-only barrier: waits lgkmcnt(0) (ds ops) but leaves global loads in flight
__device__ __forceinline__ void ldsbar() {
  __builtin_amdgcn_s_waitcnt(0xC07F);   // vmcnt(63) expcnt(7) lgkmcnt(0)
  __builtin_amdgcn_s_barrier();
}

// ---------------------------------------------------------------------------
// cAl[k*8 + sd*4 + h] = sum_f gat_w[k, h*53+f] * (sd? a_dst : a_src)[h,f]
// ---------------------------------------------------------------------------
__global__ void k_cal(const float* __restrict__ gat_w, const float* __restrict__ asrc,
                      const float* __restrict__ adst, float* __restrict__ cAl) {
  int t = threadIdx.x;
  if (t >= FDIM * 8) return;
  int k = t >> 3, r = t & 7, sd = r >> 2, h = r & 3;
  const float* av = sd ? adst : asrc;
  float acc = 0.f;
  for (int f = 0; f < FDIM; ++f) acc += gat_w[k * HF + h * FDIM + f] * av[h * FDIM + f];
  cAl[t] = acc;
}

// ---------------------------------------------------------------------------
// Pack Wp[53][432] = [gat_w | W1top-W1bot | W1bot | cAl] and bias bp[432]
// ---------------------------------------------------------------------------
__global__ void k_prep(const float* __restrict__ gat_w, const float* __restrict__ ec_w1,
                       const float* __restrict__ ec_b1, const float* __restrict__ cAl,
                       float* __restrict__ Wp, float* __restrict__ bp) {
  int idx = blockIdx.x * blockDim.x + threadIdx.x;
  if (idx < FDIM * NPACK) {
    int k = idx / NPACK, j = idx % NPACK;
    float v;
    if (j < HF)            v = gat_w[k * HF + j];
    else if (j < HF + F2)  v = ec_w1[k * F2 + (j - HF)] - ec_w1[(FDIM + k) * F2 + (j - HF)];
    else if (j < POOLW)    v = ec_w1[(FDIM + k) * F2 + (j - HF - F2)];
    else                   v = cAl[k * 8 + (j - POOLW)];
    Wp[idx] = v;
  }
  if (idx < NPACK) {
    bp[idx] = (idx >= HF && idx < HF + F2) ? ec_b1[idx - HF] : 0.f;
  }
}

// ---------------------------------------------------------------------------
// Node-linear as tiled fp32 GEMM: x[50000x53] @ Wp[53x432] + bp.
// xh output is bf16 (only k_gat consumes it).
// ---------------------------------------------------------------------------
#define GM 64
#define GN 144
#define APAD 57
__global__ __launch_bounds__(256) void k_gemm(
    const float* __restrict__ x, const float* __restrict__ Wp, const float* __restrict__ bp,
    short* __restrict__ xhb, float* __restrict__ U, float* __restrict__ V,
    float* __restrict__ alS, float* __restrict__ alD) {
  __shared__ float As[GM * APAD];
  __shared__ float Ws[FDIM * GN];
  int mb = blockIdx.x / 3, nc = blockIdx.x % 3;
  int m0 = mb * GM, n0 = nc * GN;
  int t = threadIdx.x;
  for (int idx = t; idx < GM * FDIM; idx += 256) {
    int m = idx / FDIM, k = idx % FDIM;
    int gm = m0 + m;
    As[m * APAD + k] = (gm < N_NODES) ? x[(size_t)gm * FDIM + k] : 0.f;
  }
  for (int idx = t; idx < FDIM * GN; idx += 256) {
    int k = idx / GN, n = idx % GN;
    Ws[idx] = Wp[k * NPACK + n0 + n];
  }
  __syncthreads();
  int tx = t & 15, ty = t >> 4;
  int ms = tx * 4, ns = ty * 9;
  float acc[4][9];
#pragma unroll
  for (int i = 0; i < 4; i++)
#pragma unroll
    for (int j = 0; j < 9; j++) acc[i][j] = 0.f;
  for (int k = 0; k < FDIM; k++) {
    float a0 = As[(ms + 0) * APAD + k];
    float a1 = As[(ms + 1) * APAD + k];
    float a2 = As[(ms + 2) * APAD + k];
    float a3 = As[(ms + 3) * APAD + k];
    float b[9];
#pragma unroll
    for (int j = 0; j < 9; j++) b[j] = Ws[k * GN + ns + j];
#pragma unroll
    for (int j = 0; j < 9; j++) {
      acc[0][j] += a0 * b[j];
      acc[1][j] += a1 * b[j];
      acc[2][j] += a2 * b[j];
      acc[3][j] += a3 * b[j];
    }
  }
  float bj[9];
#pragma unroll
  for (int j = 0; j < 9; j++) bj[j] = bp[n0 + ns + j];
#pragma unroll
  for (int i = 0; i < 4; i++) {
    int gm = m0 + ms + i;
    if (gm >= N_NODES) break;
#pragma unroll
    for (int j = 0; j < 9; j++) {
      int g = n0 + ns + j;
      float v = acc[i][j] + bj[j];
      if (g < HF)            xhb[(size_t)gm * HF + g] = f2bf(v);
      else if (g < HF + F2)  U[(size_t)gm * F2 + (g - HF)] = v;
      else if (g < POOLW)    V[(size_t)gm * F2 + (g - HF - F2)] = v;
      else if (g < POOLW + 4) alS[gm * 4 + (g - POOLW)] = v;
      else                   alD[gm * 4 + (g - POOLW - 4)] = v;
    }
  }
}

// ---------------------------------------------------------------------------
// CSR build: histogram, 3-phase multi-block scan, scatter
// ---------------------------------------------------------------------------
#define SCAN_BLOCKS ((N_NODES + 255) / 256)

__global__ void k_hist(const int* __restrict__ ei, const int* __restrict__ batch,
                       int* __restrict__ rp, int* __restrict__ cnt) {
  int t = blockIdx.x * blockDim.x + threadIdx.x;
  if (t < N_EDGES) atomicAdd(&rp[ei[N_EDGES + t]], 1);
  if (t < N_NODES) atomicAdd(&cnt[batch[t]], 1);
}

__global__ __launch_bounds__(256) void k_scan1(int* __restrict__ rp, int* __restrict__ bsum) {
  __shared__ int buf[256];
  int tid = threadIdx.x;
  int idx = blockIdx.x * 256 + tid;
  int v = (idx < N_NODES) ? rp[idx] : 0;
  buf[tid] = v;
  __syncthreads();
  for (int off = 1; off < 256; off <<= 1) {
    int t2 = (tid >= off) ? buf[tid - off] : 0;
    __syncthreads();
    buf[tid] += t2;
    __syncthreads();
  }
  if (idx < N_NODES) rp[idx] = buf[tid] - v;
  if (tid == 255) bsum[blockIdx.x] = buf[255];
}

__global__ __launch_bounds__(256) void k_scan2(int* __restrict__ bsum) {
  __shared__ int buf[256];
  int tid = threadIdx.x;
  int v = (tid < SCAN_BLOCKS) ? bsum[tid] : 0;
  buf[tid] = v;
  __syncthreads();
  for (int off = 1; off < 256; off <<= 1) {
    int t2 = (tid >= off) ? buf[tid - off] : 0;
    __syncthreads();
    buf[tid] += t2;
    __syncthreads();
  }
  if (tid < SCAN_BLOCKS) bsum[tid] = buf[tid] - v;
}

__global__ __launch_bounds__(256) void k_scan3(const int* __restrict__ bsum,
                                               int* __restrict__ rp, int* __restrict__ cursor) {
  int idx = blockIdx.x * 256 + threadIdx.x;
  if (idx < N_NODES) {
    int o = rp[idx] + bsum[blockIdx.x];
    rp[idx] = o;
    cursor[idx] = o;
  }
  if (idx == 0) rp[N_NODES] = N_EDGES;
}

__global__ void k_scatter(const int* __restrict__ ei, int* __restrict__ cursor,
                          int* __restrict__ colidx) {
  int e = blockIdx.x * blockDim.x + threadIdx.x;
  if (e >= N_EDGES) return;
  int d = ei[N_EDGES + e];
  int pos = atomicAdd(&cursor[d], 1);
  colidx[pos] = ei[e];
}

// ---------------------------------------------------------------------------
// GAT: wave per node; bf16 xh messages; x4-batched gather for MLP;
// register pool accumulation with flush on batch change.
// ---------------------------------------------------------------------------
#define GCH 40
__global__ __launch_bounds__(256) void k_gat(
    const short* __restrict__ xhb, const float* __restrict__ alS, const float* __restrict__ alD,
    const float* __restrict__ bias, const int* __restrict__ rp, const int* __restrict__ colidx,
    const int* __restrict__ batch, float* __restrict__ pooled) {
  int wid = threadIdx.x >> 6, lane = threadIdx.x & 63;
  int f0 = lane, f1 = lane + 64, f2 = lane + 128, f3 = lane + 192;
  bool v3 = (f3 < HF);
  bool h0a = f0 < FDIM;
  bool h1a = f1 < 2 * FDIM;
  bool h2a = f2 < 3 * FDIM;
  float bi0 = bias[f0], bi1 = bias[f1], bi2 = bias[f2], bi3 = bias[v3 ? f3 : 0];
  float r0 = 0.f, r1 = 0.f, r2 = 0.f, r3 = 0.f;
  int curb = -1;
  int i0 = blockIdx.x * GCH;
  int iend = min(i0 + GCH, N_NODES);
  for (int i = i0 + wid; i < iend; i += 4) {
    int base = rp[i], deg = rp[i + 1] - base;
    float aldi[4], esf[4];
#pragma unroll
    for (int h = 0; h < 4; h++) {
      aldi[h] = alD[i * 4 + h];
      esf[h] = leaky02(alS[i * 4 + h] + aldi[h]);
    }
    float mx[4] = {-1e30f, -1e30f, -1e30f, -1e30f};
    for (int c = lane; c < deg; c += 64) {
      int s = colidx[base + c];
#pragma unroll
      for (int h = 0; h < 4; h++) mx[h] = fmaxf(mx[h], leaky02(alS[s * 4 + h] + aldi[h]));
    }
#pragma unroll
    for (int off = 32; off >= 1; off >>= 1)
#pragma unroll
      for (int h = 0; h < 4; h++) mx[h] = fmaxf(mx[h], __shfl_xor(mx[h], off));
    float m[4], exs[4];
#pragma unroll
    for (int h = 0; h < 4; h++) { m[h] = fmaxf(mx[h], esf[h]); exs[h] = __expf(esf[h] - m[h]); }

    const short* xhi = xhb + (size_t)i * HF;
    float acc0 = (h0a ? exs[0] : exs[1]) * bf2f(xhi[f0]);
    float acc1 = (h1a ? exs[1] : exs[2]) * bf2f(xhi[f1]);
    float acc2 = (h2a ? exs[2] : exs[3]) * bf2f(xhi[f2]);
    float acc3 = v3 ? exs[3] * bf2f(xhi[f3]) : 0.f;
    float zl[4] = {0.f, 0.f, 0.f, 0.f};

    for (int c0 = 0; c0 < deg; c0 += 64) {
      int cn = min(64, deg - c0);
      int s = 0;
      float ex0 = 0.f, ex1 = 0.f, ex2 = 0.f, ex3 = 0.f;
      if (lane < cn) {
        s = colidx[base + c0 + lane];
        ex0 = __expf(leaky02(alS[s * 4 + 0] + aldi[0]) - m[0]);
        ex1 = __expf(leaky02(alS[s * 4 + 1] + aldi[1]) - m[1]);
        ex2 = __expf(leaky02(alS[s * 4 + 2] + aldi[2]) - m[2]);
        ex3 = __expf(leaky02(alS[s * 4 + 3] + aldi[3]) - m[3]);
        zl[0] += ex0; zl[1] += ex1; zl[2] += ex2; zl[3] += ex3;
      }
      // x4-batched message gather: issue 16 loads, then FMA
      for (int jj = 0; jj < cn; jj += 4) {
        int sj[4]; float a0[4], a1[4], a2[4], a3[4];
#pragma unroll
        for (int q = 0; q < 4; q++) {
          int j2 = jj + q;
          int jc = (j2 < cn) ? j2 : (cn - 1);
          bool val = j2 < cn;
          sj[q] = __shfl(s, jc);
          a0[q] = val ? __shfl(ex0, jc) : 0.f;
          a1[q] = val ? __shfl(ex1, jc) : 0.f;
          a2[q] = val ? __shfl(ex2, jc) : 0.f;
          a3[q] = val ? __shfl(ex3, jc) : 0.f;
        }
        float g0[4], g1[4], g2[4], g3[4];
#pragma unroll
        for (int q = 0; q < 4; q++) {
          const short* xr = xhb + (size_t)sj[q] * HF;
          g0[q] = bf2f(xr[f0]);
          g1[q] = bf2f(xr[f1]);
          g2[q] = bf2f(xr[f2]);
          g3[q] = v3 ? bf2f(xr[f3]) : 0.f;
        }
#pragma unroll
        for (int q = 0; q < 4; q++) {
          acc0 += (h0a ? a0[q] : a1[q]) * g0[q];
          acc1 += (h1a ? a1[q] : a2[q]) * g1[q];
          acc2 += (h2a ? a2[q] : a3[q]) * g2[q];
          if (v3) acc3 += a3[q] * g3[q];
        }
      }
    }
#pragma unroll
    for (int off = 32; off >= 1; off >>= 1)
#pragma unroll
      for (int h = 0; h < 4; h++) zl[h] += __shfl_xor(zl[h], off);
    float z[4];
#pragma unroll
    for (int h = 0; h < 4; h++) z[h] = zl[h] + exs[h] + 1e-16f;

    float o0 = fmaxf(acc0 / (h0a ? z[0] : z[1]) + bi0, 0.f);
    float o1 = fmaxf(acc1 / (h1a ? z[1] : z[2]) + bi1, 0.f);
    float o2 = fmaxf(acc2 / (h2a ? z[2] : z[3]) + bi2, 0.f);
    float o3 = v3 ? fmaxf(acc3 / z[3] + bi3, 0.f) : 0.f;
    int b = batch[i];
    if (b != curb) {
      if (curb >= 0) {
        float* pg = pooled + (size_t)curb * POOLW;
        atomicAdd(&pg[f0], r0);
        atomicAdd(&pg[f1], r1);
        atomicAdd(&pg[f2], r2);
        if (v3) atomicAdd(&pg[f3], r3);
      }
      curb = b; r0 = o0; r1 = o1; r2 = o2; r3 = o3;
    } else {
      r0 += o0; r1 += o1; r2 += o2; r3 += o3;
    }
  }
  if (curb >= 0) {
    float* pg = pooled + (size_t)curb * POOLW;
    atomicAdd(&pg[f0], r0);
    atomicAdd(&pg[f1], r1);
    atomicAdd(&pg[f2], r2);
    if (v3) atomicAdd(&pg[f3], r3);
  }
}

// ---------------------------------------------------------------------------
// GIN (1): gather-sum agg = x + sum_neighbors x
// ---------------------------------------------------------------------------
__global__ __launch_bounds__(256) void k_ginagg(
    const float* __restrict__ x, const int* __restrict__ rp, const int* __restrict__ colidx,
    float* __restrict__ agg) {
  int wid = threadIdx.x >> 6, lane = threadIdx.x & 63;
  int i = blockIdx.x * 4 + wid;
  if (i >= N_NODES) return;
  int base = rp[i], deg = rp[i + 1] - base;
  float hk = (lane < FDIM) ? x[(size_t)i * FDIM + lane] : 0.f;
  int c = 0;
  for (; c + 4 <= deg; c += 4) {
    int s0 = colidx[base + c + 0];
    int s1 = colidx[base + c + 1];
    int s2 = colidx[base + c + 2];
    int s3 = colidx[base + c + 3];
    if (lane < FDIM) {
      float v0 = x[(size_t)s0 * FDIM + lane];
      float v1 = x[(size_t)s1 * FDIM + lane];
      float v2 = x[(size_t)s2 * FDIM + lane];
      float v3 = x[(size_t)s3 * FDIM + lane];
      hk += (v0 + v1) + (v2 + v3);
    }
  }
  for (; c < deg; c++) {
    int s = colidx[base + c];
    if (lane < FDIM) hk += x[(size_t)s * FDIM + lane];
  }
  if (lane < FDIM) agg[(size_t)i * FDIM + lane] = hk;
}

// ---------------------------------------------------------------------------
// GIN (2): h1g = relu(agg @ w1 + b1)
// ---------------------------------------------------------------------------
__global__ __launch_bounds__(256) void k_gin1(
    const float* __restrict__ agg, const float* __restrict__ w1, const float* __restrict__ b1,
    float* __restrict__ h1g) {
  __shared__ float As[64 * APAD];
  __shared__ float Ws[FDIM * 112];
  int m0 = blockIdx.x * 64;
  int t = threadIdx.x;
  for (int idx = t; idx < 64 * FDIM; idx += 256) {
    int m = idx / FDIM, k = idx % FDIM;
    int gm = m0 + m;
    As[m * APAD + k] = (gm < N_NODES) ? agg[(size_t)gm * FDIM + k] : 0.f;
  }
  for (int idx = t; idx < FDIM * 112; idx += 256) {
    int k = idx / 112, n = idx % 112;
    Ws[idx] = (n < F2) ? w1[k * F2 + n] : 0.f;
  }
  __syncthreads();
  int tx = t & 15, ty = t >> 4;
  int ms = tx * 4, ns = ty * 7;
  float acc[4][7];
#pragma unroll
  for (int i = 0; i < 4; i++)
#pragma unroll
    for (int j = 0; j < 7; j++) acc[i][j] = 0.f;
  for (int k = 0; k < FDIM; k++) {
    float a0 = As[(ms + 0) * APAD + k];
    float a1 = As[(ms + 1) * APAD + k];
    float a2 = As[(ms + 2) * APAD + k];
    float a3 = As[(ms + 3) * APAD + k];
    float b[7];
#pragma unroll
    for (int j = 0; j < 7; j++) b[j] = Ws[k * 112 + ns + j];
#pragma unroll
    for (int j = 0; j < 7; j++) {
      acc[0][j] += a0 * b[j];
      acc[1][j] += a1 * b[j];
      acc[2][j] += a2 * b[j];
      acc[3][j] += a3 * b[j];
    }
  }
#pragma unroll
  for (int i = 0; i < 4; i++) {
    int gm = m0 + ms + i;
    if (gm >= N_NODES) break;
#pragma unroll
    for (int j = 0; j < 7; j++) {
      int n = ns + j;
      if (n < F2) h1g[(size_t)gm * F2 + n] = fmaxf(acc[i][j] + b1[n], 0.f);
    }
  }
}

// ---------------------------------------------------------------------------
// GIN (3): h2 = relu(h1g @ w2 + b2) + pooled accumulation (LDS psum)
// ---------------------------------------------------------------------------
#define A2PAD 111
__global__ __launch_bounds__(256) void k_gin2(
    const float* __restrict__ h1g, const float* __restrict__ w2, const float* __restrict__ b2,
    const int* __restrict__ batch, float* __restrict__ pooled) {
  __shared__ float As[64 * A2PAD];
  __shared__ float Ws[F2 * 112];
  __shared__ float psum[4 * 112];
  int m0 = blockIdx.x * 64;
  int t = threadIdx.x;
  for (int idx = t; idx < 4 * 112; idx += 256) psum[idx] = 0.f;
  for (int idx = t; idx < 64 * F2; idx += 256) {
    int m = idx / F2, k = idx % F2;
    int gm = m0 + m;
    As[m * A2PAD + k] = (gm < N_NODES) ? h1g[(size_t)gm * F2 + k] : 0.f;
  }
  for (int idx = t; idx < F2 * 112; idx += 256) {
    int k = idx / 112, n = idx % 112;
    Ws[idx] = (n < F2) ? w2[k * F2 + n] : 0.f;
  }
  __syncthreads();
  int tx = t & 15, ty = t >> 4;
  int ms = tx * 4, ns = ty * 7;
  float acc[4][7];
#pragma unroll
  for (int i = 0; i < 4; i++)
#pragma unroll
    for (int j = 0; j < 7; j++) acc[i][j] = 0.f;
  for (int k = 0; k < F2; k++) {
    float a0 = As[(ms + 0) * A2PAD + k];
    float a1 = As[(ms + 1) * A2PAD + k];
    float a2 = As[(ms + 2) * A2PAD + k];
    float a3 = As[(ms + 3) * A2PAD + k];
    float b[7];
#pragma unroll
    for (int j = 0; j < 7; j++) b[j] = Ws[k * 112 + ns + j];
#pragma unroll
    for (int j = 0; j < 7; j++) {
      acc[0][j] += a0 * b[j];
      acc[1][j] += a1 * b[j];
      acc[2][j] += a2 * b[j];
      acc[3][j] += a3 * b[j];
    }
  }
  float b2n[7];
#pragma unroll
  for (int j = 0; j < 7; j++) {
    int n = ns + j;
    b2n[j] = (n < F2) ? b2[n] : 0.f;
  }
  int bmin = batch[m0];
  float pj[7];
#pragma unroll
  for (int j = 0; j < 7; j++) pj[j] = 0.f;
  int curb = -1;
#pragma unroll
  for (int i = 0; i < 4; i++) {
    int gm = m0 + ms + i;
    if (gm >= N_NODES) break;
    int b = batch[gm];
    if (b != curb) {
      if (curb >= 0) {
        int slot = curb - bmin;
        if (slot >= 0 && slot < 4) {
#pragma unroll
          for (int j = 0; j < 7; j++)
            if (ns + j < F2) atomicAdd(&psum[slot * 112 + ns + j], pj[j]);
        } else {
          float* pg = pooled + (size_t)curb * POOLW + HF;
#pragma unroll
          for (int j = 0; j < 7; j++)
            if (ns + j < F2) atomicAdd(&pg[ns + j], pj[j]);
        }
      }
      curb = b;
#pragma unroll
      for (int j = 0; j < 7; j++)
        pj[j] = (ns + j < F2) ? fmaxf(acc[i][j] + b2n[j], 0.f) : 0.f;
    } else {
#pragma unroll
      for (int j = 0; j < 7; j++)
        if (ns + j < F2) pj[j] += fmaxf(acc[i][j] + b2n[j], 0.f);
    }
  }
  if (curb >= 0) {
    int slot = curb - bmin;
    if (slot >= 0 && slot < 4) {
#pragma unroll
      for (int j = 0; j < 7; j++)
        if (ns + j < F2) atomicAdd(&psum[slot * 112 + ns + j], pj[j]);
    } else {
      float* pg = pooled + (size_t)curb * POOLW + HF;
#pragma unroll
      for (int j = 0; j < 7; j++)
        if (ns + j < F2) atomicAdd(&pg[ns + j], pj[j]);
    }
  }
  __syncthreads();
  for (int idx = t; idx < 4 * 112; idx += 256) {
    int slot = idx / 112, n = idx % 112;
    float v = psum[idx];
    int b = bmin + slot;
    if (n < F2 && b < BATCH && v != 0.f)
      atomicAdd(&pooled[(size_t)b * POOLW + HF + n], v);
  }
}

// ---------------------------------------------------------------------------
// EdgeConv v7: pipelined MFMA. Flattened (node,tile) iterator; double-buffer
// LDS; ONE light barrier per tile (lgkmcnt-only — global prefetch stays in
// flight); next tile's V rows (+ next node's U) prefetched before the
// barrier so the gather overlaps current tile's MFMA + reduce.
// ---------------------------------------------------------------------------
#define ECH 25
__global__ __launch_bounds__(256) void k_ec(
    const float* __restrict__ U, const float* __restrict__ V,
    const float* __restrict__ w2, const float* __restrict__ b2,
    const int* __restrict__ rp, const int* __restrict__ colidx,
    const int* __restrict__ batch, float* __restrict__ pooled) {
  const int t = threadIdx.x;
  const int lane = t & 63, wid = t >> 6;
  const int n16 = lane & 15, quad = lane >> 4;
  const int nt = (wid == 3) ? 1 : 2;   // u-tile 7 is all-pad

  short8 Bh[2][4];
  for (int tt = 0; tt < 2; tt++) {
    int ucol = (wid * 2 + tt) * 16 + n16;
    for (int kc = 0; kc < 4; kc++) {
      short8 vh;
#pragma unroll
      for (int jv = 0; jv < 8; jv++) {
        int kk = kc * 32 + quad * 8 + jv;
        float w = (ucol < F2 && kk < F2) ? w2[kk * F2 + ucol] : 0.f;
        vh[jv] = f2bf(w);
      }
      Bh[tt][kc] = vh;
    }
  }
  float b2v[2];
#pragma unroll
  for (int tt = 0; tt < 2; tt++) {
    int u = (wid * 2 + tt) * 16 + n16;
    b2v[tt] = (u < F2) ? b2[u] : 0.f;
  }

  __shared__ short hs[2][16 * 16 * 8];   // 2 x 4 KB, fragment order
  union SU { short8 s; unsigned u[4]; };
  const int es = t & 15, kg = t >> 4;    // staging roles
  const int k0 = kg * 8;

  float sm0 = 0.f, sm1 = 0.f;
  int curb = -1;
  const int u0 = (wid * 2) * 16 + n16;
  const int u1 = (wid * 2 + 1) * 16 + n16;

  const int i0 = blockIdx.x * ECH;
  const int iend = min(i0 + ECH, N_NODES);

  // iterator init: first non-empty node (uniform across block)
  int i = i0, base = 0, deg = 0;
  bool have = false;
  for (; i < iend; i++) {
    base = rp[i]; deg = rp[i + 1] - base;
    if (deg > 0) { have = true; break; }
  }
  float2 pv[4], pu[4];
  if (have) {
    const float2* up = (const float2*)(U + (size_t)i * F2 + k0);
#pragma unroll
    for (int p = 0; p < 4; p++) pu[p] = up[p];
    int s = colidx[base + ((es < deg) ? es : 0)];
    const float2* vp = (const float2*)(V + (size_t)s * F2 + k0);
#pragma unroll
    for (int p = 0; p < 4; p++) pv[p] = vp[p];
  }
  float Uc[8];
  float vmax0 = -1e30f, vmax1 = -1e30f;
  int tb = 0, parity = 0;
  while (have) {
    if (tb == 0) {
#pragma unroll
      for (int p = 0; p < 4; p++) { Uc[2 * p] = pu[p].x; Uc[2 * p + 1] = pu[p].y; }
    }
    // convert current tile (waits on pv here — overlapped by prev MFMA)
    SU w;
#pragma unroll
    for (int p = 0; p < 4; p++) {
      bool kv = (k0 + 2 * p) < F2;
      float h0 = kv ? fmaxf(Uc[2 * p] + pv[p].x, 0.f) : 0.f;
      float h1 = kv ? fmaxf(Uc[2 * p + 1] + pv[p].y, 0.f) : 0.f;
      w.u[p] = pk2(h0, h1);
    }
    // next tile coords (uniform)
    int ni = i, ntb = tb + 1, nbase = base, ndeg = deg;
    bool nhave = true;
    if (ntb * 16 >= deg) {
      ntb = 0; nhave = false;
      for (ni = i + 1; ni < iend; ni++) {
        nbase = rp[ni]; ndeg = rp[ni + 1] - nbase;
        if (ndeg > 0) { nhave = true; break; }
      }
    }
    // store LDS
    *(short8*)&hs[parity][(kg * 16 + es) * 8] = w.s;
    // prefetch next tile BEFORE barrier (stays in flight across it)
    if (nhave) {
      if (ntb == 0) {
        const float2* up = (const float2*)(U + (size_t)ni * F2 + k0);
#pragma unroll
        for (int p = 0; p < 4; p++) pu[p] = up[p];
      }
      int eg2 = ntb * 16 + es;
      int s2 = colidx[nbase + ((eg2 < ndeg) ? eg2 : 0)];
      const float2* vp = (const float2*)(V + (size_t)s2 * F2 + k0);
#pragma unroll
      for (int p = 0; p < 4; p++) pv[p] = vp[p];
    }
    ldsbar();   // lgkmcnt(0) + s_barrier: no vmcnt drain
    // MFMA on current tile
    f32x4 a0 = {0.f, 0.f, 0.f, 0.f}, a1 = {0.f, 0.f, 0.f, 0.f};
#pragma unroll
    for (int kc = 0; kc < 4; kc++) {
      short8 af = *(const short8*)&hs[parity][((kc * 4 + quad) * 16 + n16) * 8];
      a0 = __builtin_amdgcn_mfma_f32_16x16x32_bf16(af, Bh[0][kc], a0, 0, 0, 0);
      if (nt > 1)
        a1 = __builtin_amdgcn_mfma_f32_16x16x32_bf16(af, Bh[1][kc], a1, 0, 0, 0);
    }
    float m0 = -1e30f, m1 = -1e30f;
#pragma unroll
    for (int r = 0; r < 4; r++) {
      int er = tb * 16 + quad * 4 + r;
      if (er < deg) { m0 = fmaxf(m0, a0[r]); m1 = fmaxf(m1, a1[r]); }
    }
    m0 = fmaxf(m0, __shfl_xor(m0, 16)); m0 = fmaxf(m0, __shfl_xor(m0, 32));
    m1 = fmaxf(m1, __shfl_xor(m1, 16)); m1 = fmaxf(m1, __shfl_xor(m1, 32));
    vmax0 = fmaxf(vmax0, m0);
    vmax1 = fmaxf(vmax1, m1);
    // node complete?
    if (ni != i) {
      float o0 = fmaxf(vmax0 + b2v[0], 0.f);
      float o1 = fmaxf(vmax1 + b2v[1], 0.f);
      int b = batch[i];
      if (b != curb) {
        if (curb >= 0 && quad == 0) {
          float* pg = pooled + (size_t)curb * POOLW + HF + F2;
          if (u0 < F2) atomicAdd(&pg[u0], sm0);
          if (nt > 1 && u1 < F2) atomicAdd(&pg[u1], sm1);
        }
        curb = b; sm0 = o0; sm1 = o1;
      } else {
        sm0 += o0; sm1 += o1;
      }
      vmax0 = -1e30f; vmax1 = -1e30f;
    }
    i = ni; tb = ntb; base = nbase; deg = ndeg; have = nhave; parity ^= 1;
  }
  if (curb >= 0 && quad == 0) {
    float* pg = pooled + (size_t)curb * POOLW + HF + F2;
    if (u0 < F2) atomicAdd(&pg[u0], sm0);
    if (nt > 1 && u1 < F2) atomicAdd(&pg[u1], sm1);
  }
}

// ---------------------------------------------------------------------------
// mean-pool divide
// ---------------------------------------------------------------------------
__global__ void k_pooldiv(float* __restrict__ pooled, const int* __restrict__ cnt) {
  int t = blockIdx.x * blockDim.x + threadIdx.x;
  if (t >= BATCH * POOLW) return;
  int b = t / POOLW;
  pooled[t] /= fmaxf((float)cnt[b], 1.f);
}

// ---------------------------------------------------------------------------
// Per-graph heads: block g computes all three 2-layer MLPs -> cat[g][384]
// ---------------------------------------------------------------------------
__global__ __launch_bounds__(256) void k_heads(
    const float* __restrict__ pooled,
    const float* __restrict__ fg1_w, const float* __restrict__ fg1_b,
    const float* __restrict__ fg2_w, const float* __restrict__ fg2_b,
    const float* __restrict__ fg3_w, const float* __restrict__ fg3_b,
    const float* __restrict__ fg4_w, const float* __restrict__ fg4_b,
    const float* __restrict__ fg5_w, const float* __restrict__ fg5_b,
    const float* __restrict__ fg6_w, const float* __restrict__ fg6_b,
    float* __restrict__ cat) {
  int g = blockIdx.x, t = threadIdx.x;
  __shared__ float in[POOLW];
  __shared__ float mid[256];
  for (int idx = t; idx < POOLW; idx += 256) in[idx] = pooled[(size_t)g * POOLW + idx];
  __syncthreads();
  const float* w1s[3] = {fg1_w, fg3_w, fg5_w};
  const float* b1s[3] = {fg1_b, fg3_b, fg5_b};
  const float* w2s[3] = {fg2_w, fg4_w, fg6_w};
  const float* b2s[3] = {fg2_b, fg4_b, fg6_b};
  const int off[4] = {0, HF, HF + F2, POOLW};
  for (int br = 0; br < 3; br++) {
    int kin = off[br + 1] - off[br];
    const float* iv = &in[off[br]];
    float a = b1s[br][t];
    const float* W = w1s[br];
    for (int k = 0; k < kin; k++) a += iv[k] * W[k * 256 + t];
    mid[t] = fmaxf(a, 0.f);
    __syncthreads();
    if (t < 128) {
      float b = b2s[br][t];
      const float* W2 = w2s[br];
      for (int k = 0; k < 256; k++) b += mid[k] * W2[k * 128 + t];
      cat[(size_t)g * 384 + br * 128 + t] = fmaxf(b, 0.f);
    }
    __syncthreads();
  }
}

// ---------------------------------------------------------------------------
// Final MLP: cat[384] -> 128 -> 64 -> 1 sigmoid, block per graph
// ---------------------------------------------------------------------------
__global__ __launch_bounds__(256) void k_final(
    const float* __restrict__ cat,
    const float* __restrict__ fc1_w, const float* __restrict__ fc1_b,
    const float* __restrict__ fc2_w, const float* __restrict__ fc2_b,
    const float* __restrict__ out_w, const float* __restrict__ out_b,
    float* __restrict__ out) {
  int g = blockIdx.x, t = threadIdx.x;
  __shared__ float hin[384];
  __shared__ float h1[128];
  __shared__ float h2[64];
  for (int idx = t; idx < 384; idx += 256) hin[idx] = cat[(size_t)g * 384 + idx];
  __syncthreads();
  if (t < 128) {
    float a = fc1_b[t];
    for (int k = 0; k < 384; k++) a += hin[k] * fc1_w[k * 128 + t];
    h1[t] = fmaxf(a, 0.f);
  }
  __syncthreads();
  if (t < 64) {
    float a = fc2_b[t];
    for (int k = 0; k < 128; k++) a += h1[k] * fc2_w[k * 64 + t];
    h2[t] = fmaxf(a, 0.f);
  }
  __syncthreads();
  if (t == 0) {
    float a = out_b[0];
    for (int k = 0; k < 64; k++) a += h2[k] * out_w[k];
    out[g] = 1.f / (1.f + __expf(-a));
  }
}

// ---------------------------------------------------------------------------
extern "C" void kernel_launch(void* const* d_in, const int* in_sizes, int n_in,
                              void* d_out, int out_size, void* d_ws, size_t ws_size,
                              hipStream_t stream) {
  const float* x      = (const float*)d_in[0];
  const int*   ei     = (const int*)d_in[1];
  const int*   batch  = (const int*)d_in[2];
  const float* gat_w  = (const float*)d_in[3];
  const float* asrc   = (const float*)d_in[4];
  const float* adst   = (const float*)d_in[5];
  const float* gat_b  = (const float*)d_in[6];
  const float* gin_w1 = (const float*)d_in[7];
  const float* gin_b1 = (const float*)d_in[8];
  const float* gin_w2 = (const float*)d_in[9];
  const float* gin_b2 = (const float*)d_in[10];
  const float* ec_w1  = (const float*)d_in[11];
  const float* ec_b1  = (const float*)d_in[12];
  const float* ec_w2  = (const float*)d_in[13];
  const float* ec_b2  = (const float*)d_in[14];
  const float* fg1_w = (const float*)d_in[15]; const float* fg1_b = (const float*)d_in[16];
  const float* fg2_w = (const float*)d_in[17]; const float* fg2_b = (const float*)d_in[18];
  const float* fg3_w = (const float*)d_in[19]; const float* fg3_b = (const float*)d_in[20];
  const float* fg4_w = (const float*)d_in[21]; const float* fg4_b = (const float*)d_in[22];
  const float* fg5_w = (const float*)d_in[23]; const float* fg5_b = (const float*)d_in[24];
  const float* fg6_w = (const float*)d_in[25]; const float* fg6_b = (const float*)d_in[26];
  const float* fc1_w = (const float*)d_in[27]; const float* fc1_b = (const float*)d_in[28];
  const float* fc2_w = (const float*)d_in[29]; const float* fc2_b = (const float*)d_in[30];
  const float* out_w = (const float*)d_in[31]; const float* out_b = (const float*)d_in[32];
  float* out = (float*)d_out;

  char* ws = (char*)d_ws;
  size_t off = 0;
  auto alloc = [&](size_t bytes) -> void* {
    void* p = ws + off;
    off = (off + bytes + 255) & ~(size_t)255;
    return p;
  };
  // --- zero region (one memset): rp | cnt | pooled ---
  size_t zoff0 = off;
  int*   rp     = (int*)alloc((N_NODES + 1) * sizeof(int));
  int*   cnt    = (int*)alloc(BATCH * sizeof(int));
  float* pooled = (float*)alloc((size_t)BATCH * POOLW * sizeof(float));
  size_t zbytes = off - zoff0;
  // --- rest ---
  int*   cursor = (int*)alloc(N_NODES * sizeof(int));
  int*   bsum   = (int*)alloc(256 * sizeof(int));
  int*   colidx = (int*)alloc(N_EDGES * sizeof(int));
  short* xhb    = (short*)alloc((size_t)N_NODES * HF * sizeof(short));
  float* alS    = (float*)alloc((size_t)N_NODES * 4 * sizeof(float));
  float* alD    = (float*)alloc((size_t)N_NODES * 4 * sizeof(float));
  float* Ubuf   = (float*)alloc((size_t)N_NODES * F2 * sizeof(float));
  float* Vbuf   = (float*)alloc((size_t)N_NODES * F2 * sizeof(float));
  float* cAl    = (float*)alloc(FDIM * 8 * sizeof(float));
  float* Wp     = (float*)alloc((size_t)FDIM * NPACK * sizeof(float));
  float* bpk    = (float*)alloc(NPACK * sizeof(float));
  float* cat    = (float*)alloc((size_t)BATCH * 384 * sizeof(float));
  (void)ws_size; (void)in_sizes; (void)n_in; (void)out_size;
  // GIN scratch aliases U/V (dead after k_ec; stream order serializes):
  float* agg = Ubuf;                            // 50000*53 floats (10.6 MB)
  float* h1g = Ubuf + (size_t)N_NODES * FDIM;   // 50000*106 floats, spills into Vbuf region

  hipMemsetAsync(ws + zoff0, 0, zbytes, stream);

  k_cal<<<1, 448, 0, stream>>>(gat_w, asrc, adst, cAl);
  k_prep<<<(FDIM * NPACK + 255) / 256, 256, 0, stream>>>(gat_w, ec_w1, ec_b1, cAl, Wp, bpk);
  k_gemm<<<((N_NODES + GM - 1) / GM) * 3, 256, 0, stream>>>(x, Wp, bpk,
                                                            xhb, Ubuf, Vbuf, alS, alD);
  k_hist<<<(N_EDGES + 255) / 256, 256, 0, stream>>>(ei, batch, rp, cnt);
  k_scan1<<<SCAN_BLOCKS, 256, 0, stream>>>(rp, bsum);
  k_scan2<<<1, 256, 0, stream>>>(bsum);
  k_scan3<<<SCAN_BLOCKS, 256, 0, stream>>>(bsum, rp, cursor);
  k_scatter<<<(N_EDGES + 255) / 256, 256, 0, stream>>>(ei, cursor, colidx);

  k_gat<<<(N_NODES + GCH - 1) / GCH, 256, 0, stream>>>(xhb, alS, alD, gat_b, rp, colidx, batch, pooled);
  k_ec<<<(N_NODES + ECH - 1) / ECH, 256, 0, stream>>>(Ubuf, Vbuf, ec_w2, ec_b2, rp, colidx, batch, pooled);
  // GIN after k_ec (agg/h1g alias U/V)
  k_ginagg<<<(N_NODES + 3) / 4, 256, 0, stream>>>(x, rp, colidx, agg);
  k_gin1<<<(N_NODES + 63) / 64, 256, 0, stream>>>(agg, gin_w1, gin_b1, h1g);
  k_gin2<<<(N_NODES + 63) / 64, 256, 0, stream>>>(h1g, gin_w2, gin_b2, batch, pooled);

  k_pooldiv<<<(BATCH * POOLW + 255) / 256, 256, 0, stream>>>(pooled, cnt);

  k_heads<<<BATCH, 256, 0, stream>>>(pooled, fg1_w, fg1_b, fg2_w, fg2_b, fg3_w, fg3_b,
                                     fg4_w, fg4_b, fg5_w, fg5_b, fg6_w, fg6_b, cat);
  k_final<<<BATCH, 256, 0, stream>>>(cat, fc1_w, fc1_b, fc2_w, fc2_b, out_w, out_b, out);
}

// Round 8
// 773.482 us; speedup vs baseline: 2.1658x; 1.1463x over previous
//
#include <hip/hip_runtime.h>
#include <hip/hip_bf16.h>
#include <math.h>

#define N_NODES 50000
#define N_EDGES 800000
#define FDIM 53
#define BATCH 128
#define HF 212   /* H*F */
#define F2 106   /* 2F  */
#define POOLW 424 /* 212+106+106 */
#define NPACK 432 /* 212 + 106 + 106 + 8 */
#define PSTR 32  /* padded bin stride (ints) = 128 B: one L2 line per node */

typedef __attribute__((ext_vector_type(8))) short short8;
typedef __attribute__((ext_vector_type(4))) float f32x4;

__device__ __forceinline__ float leaky02(float x){ return x >= 0.f ? x : 0.2f * x; }

__device__ __forceinline__ short f2bf(float x) {
  unsigned u = __float_as_uint(x);
  unsigned r = (u + 0x7fffu + ((u >> 16) & 1u)) >> 16;
  return (short)r;
}
__device__ __forceinline__ float bf2f(short b) {
  return __uint_as_float(((unsigned)(unsigned short)b) << 16);
}
// packed pair f32x2 -> bf16x2 (v_cvt_pk_bf16_f32, RNE)
__device__ __forceinline__ unsigned pk2(float a, float b) {
  union { __hip_bfloat162 h; unsigned u; } c;
  c.h = __float22bfloat162_rn(make_float2(a, b));
  return c.u;
}
// LDS-only barrier: waits lgkmcnt(0) (ds ops) but leaves global loads in flight
__device__ __forceinline__ void ldsbar() {
  __builtin_amdgcn_s_waitcnt(0xC07F);   // vmcnt(63) expcnt(7) lgkmcnt(0)
  __builtin_amdgcn_s_barrier();
}

// ---------------------------------------------------------------------------
// cAl[k*8 + sd*4 + h] = sum_f gat_w[k, h*53+f] * (sd? a_dst : a_src)[h,f]
// ---------------------------------------------------------------------------
__global__ void k_cal(const float* __restrict__ gat_w, const float* __restrict__ asrc,
                      const float* __restrict__ adst, float* __restrict__ cAl) {
  int t = threadIdx.x;
  if (t >= FDIM * 8) return;
  int k = t >> 3, r = t & 7, sd = r >> 2, h = r & 3;
  const float* av = sd ? adst : asrc;
  float acc = 0.f;
  for (int f = 0; f < FDIM; ++f) acc += gat_w[k * HF + h * FDIM + f] * av[h * FDIM + f];
  cAl[t] = acc;
}

// ---------------------------------------------------------------------------
// Pack Wp[53][432] = [gat_w | W1top-W1bot | W1bot | cAl] and bias bp[432]
// ---------------------------------------------------------------------------
__global__ void k_prep(const float* __restrict__ gat_w, const float* __restrict__ ec_w1,
                       const float* __restrict__ ec_b1, const float* __restrict__ cAl,
                       float* __restrict__ Wp, float* __restrict__ bp) {
  int idx = blockIdx.x * blockDim.x + threadIdx.x;
  if (idx < FDIM * NPACK) {
    int k = idx / NPACK, j = idx % NPACK;
    float v;
    if (j < HF)            v = gat_w[k * HF + j];
    else if (j < HF + F2)  v = ec_w1[k * F2 + (j - HF)] - ec_w1[(FDIM + k) * F2 + (j - HF)];
    else if (j < POOLW)    v = ec_w1[(FDIM + k) * F2 + (j - HF - F2)];
    else                   v = cAl[k * 8 + (j - POOLW)];
    Wp[idx] = v;
  }
  if (idx < NPACK) {
    bp[idx] = (idx >= HF && idx < HF + F2) ? ec_b1[idx - HF] : 0.f;
  }
}

// ---------------------------------------------------------------------------
// Node-linear as tiled fp32 GEMM: x[50000x53] @ Wp[53x432] + bp.
// xh output is bf16 (only k_gat consumes it).
// ---------------------------------------------------------------------------
#define GM 64
#define GN 144
#define APAD 57
__global__ __launch_bounds__(256) void k_gemm(
    const float* __restrict__ x, const float* __restrict__ Wp, const float* __restrict__ bp,
    short* __restrict__ xhb, float* __restrict__ U, float* __restrict__ V,
    float* __restrict__ alS, float* __restrict__ alD) {
  __shared__ float As[GM * APAD];
  __shared__ float Ws[FDIM * GN];
  int mb = blockIdx.x / 3, nc = blockIdx.x % 3;
  int m0 = mb * GM, n0 = nc * GN;
  int t = threadIdx.x;
  for (int idx = t; idx < GM * FDIM; idx += 256) {
    int m = idx / FDIM, k = idx % FDIM;
    int gm = m0 + m;
    As[m * APAD + k] = (gm < N_NODES) ? x[(size_t)gm * FDIM + k] : 0.f;
  }
  for (int idx = t; idx < FDIM * GN; idx += 256) {
    int k = idx / GN, n = idx % GN;
    Ws[idx] = Wp[k * NPACK + n0 + n];
  }
  __syncthreads();
  int tx = t & 15, ty = t >> 4;
  int ms = tx * 4, ns = ty * 9;
  float acc[4][9];
#pragma unroll
  for (int i = 0; i < 4; i++)
#pragma unroll
    for (int j = 0; j < 9; j++) acc[i][j] = 0.f;
  for (int k = 0; k < FDIM; k++) {
    float a0 = As[(ms + 0) * APAD + k];
    float a1 = As[(ms + 1) * APAD + k];
    float a2 = As[(ms + 2) * APAD + k];
    float a3 = As[(ms + 3) * APAD + k];
    float b[9];
#pragma unroll
    for (int j = 0; j < 9; j++) b[j] = Ws[k * GN + ns + j];
#pragma unroll
    for (int j = 0; j < 9; j++) {
      acc[0][j] += a0 * b[j];
      acc[1][j] += a1 * b[j];
      acc[2][j] += a2 * b[j];
      acc[3][j] += a3 * b[j];
    }
  }
  float bj[9];
#pragma unroll
  for (int j = 0; j < 9; j++) bj[j] = bp[n0 + ns + j];
#pragma unroll
  for (int i = 0; i < 4; i++) {
    int gm = m0 + ms + i;
    if (gm >= N_NODES) break;
#pragma unroll
    for (int j = 0; j < 9; j++) {
      int g = n0 + ns + j;
      float v = acc[i][j] + bj[j];
      if (g < HF)            xhb[(size_t)gm * HF + g] = f2bf(v);
      else if (g < HF + F2)  U[(size_t)gm * F2 + (g - HF)] = v;
      else if (g < POOLW)    V[(size_t)gm * F2 + (g - HF - F2)] = v;
      else if (g < POOLW + 4) alS[gm * 4 + (g - POOLW)] = v;
      else                   alD[gm * 4 + (g - POOLW - 4)] = v;
    }
  }
}

// ---------------------------------------------------------------------------
// CSR build with L2-line-padded bins: hist -> scan (compacts to rp, turns
// padded slot into scatter cursor) -> scatter. Graph counts via sorted-batch
// boundary detection (no atomics).
// ---------------------------------------------------------------------------
#define SCAN_BLOCKS ((N_NODES + 255) / 256)

__global__ void k_hist(const int* __restrict__ ei, int* __restrict__ histP) {
  int t = blockIdx.x * blockDim.x + threadIdx.x;
  if (t < N_EDGES) atomicAdd(&histP[ei[N_EDGES + t] << 5], 1);
}

__global__ void k_bnd(const int* __restrict__ batch, int* __restrict__ start) {
  int t = blockIdx.x * blockDim.x + threadIdx.x;
  if (t >= N_NODES) return;
  int b = batch[t];
  if (t == 0)
    for (int g = 0; g <= b; g++) start[g] = 0;
  int bn = (t + 1 < N_NODES) ? batch[t + 1] : BATCH;
  for (int g = b + 1; g <= bn; g++) start[g] = t + 1;
}

__global__ __launch_bounds__(256) void k_scan1(const int* __restrict__ histP,
                                               int* __restrict__ rp, int* __restrict__ bsum) {
  __shared__ int buf[256];
  int tid = threadIdx.x;
  int idx = blockIdx.x * 256 + tid;
  int v = (idx < N_NODES) ? histP[idx << 5] : 0;
  buf[tid] = v;
  __syncthreads();
  for (int off = 1; off < 256; off <<= 1) {
    int t2 = (tid >= off) ? buf[tid - off] : 0;
    __syncthreads();
    buf[tid] += t2;
    __syncthreads();
  }
  if (idx < N_NODES) rp[idx] = buf[tid] - v;
  if (tid == 255) bsum[blockIdx.x] = buf[255];
}

__global__ __launch_bounds__(256) void k_scan2(int* __restrict__ bsum) {
  __shared__ int buf[256];
  int tid = threadIdx.x;
  int v = (tid < SCAN_BLOCKS) ? bsum[tid] : 0;
  buf[tid] = v;
  __syncthreads();
  for (int off = 1; off < 256; off <<= 1) {
    int t2 = (tid >= off) ? buf[tid - off] : 0;
    __syncthreads();
    buf[tid] += t2;
    __syncthreads();
  }
  if (tid < SCAN_BLOCKS) bsum[tid] = buf[tid] - v;
}

__global__ __launch_bounds__(256) void k_scan3(const int* __restrict__ bsum,
                                               int* __restrict__ rp, int* __restrict__ histP) {
  int idx = blockIdx.x * 256 + threadIdx.x;
  if (idx < N_NODES) {
    int o = rp[idx] + bsum[blockIdx.x];
    rp[idx] = o;
    histP[idx << 5] = o;   // becomes the (padded) scatter cursor
  }
  if (idx == 0) rp[N_NODES] = N_EDGES;
}

__global__ void k_scatter(const int* __restrict__ ei, int* __restrict__ histP,
                          int* __restrict__ colidx) {
  int e = blockIdx.x * blockDim.x + threadIdx.x;
  if (e >= N_EDGES) return;
  int d = ei[N_EDGES + e];
  int pos = atomicAdd(&histP[d << 5], 1);
  colidx[pos] = ei[e];
}

// ---------------------------------------------------------------------------
// GAT: wave per node; bf16 xh messages; x4-batched gather;
// register pool accumulation with flush on batch change.
// ---------------------------------------------------------------------------
#define GCH 40
__global__ __launch_bounds__(256) void k_gat(
    const short* __restrict__ xhb, const float* __restrict__ alS, const float* __restrict__ alD,
    const float* __restrict__ bias, const int* __restrict__ rp, const int* __restrict__ colidx,
    const int* __restrict__ batch, float* __restrict__ pooled) {
  int wid = threadIdx.x >> 6, lane = threadIdx.x & 63;
  int f0 = lane, f1 = lane + 64, f2 = lane + 128, f3 = lane + 192;
  bool v3 = (f3 < HF);
  bool h0a = f0 < FDIM;
  bool h1a = f1 < 2 * FDIM;
  bool h2a = f2 < 3 * FDIM;
  float bi0 = bias[f0], bi1 = bias[f1], bi2 = bias[f2], bi3 = bias[v3 ? f3 : 0];
  float r0 = 0.f, r1 = 0.f, r2 = 0.f, r3 = 0.f;
  int curb = -1;
  int i0 = blockIdx.x * GCH;
  int iend = min(i0 + GCH, N_NODES);
  for (int i = i0 + wid; i < iend; i += 4) {
    int base = rp[i], deg = rp[i + 1] - base;
    float aldi[4], esf[4];
#pragma unroll
    for (int h = 0; h < 4; h++) {
      aldi[h] = alD[i * 4 + h];
      esf[h] = leaky02(alS[i * 4 + h] + aldi[h]);
    }
    float mx[4] = {-1e30f, -1e30f, -1e30f, -1e30f};
    for (int c = lane; c < deg; c += 64) {
      int s = colidx[base + c];
#pragma unroll
      for (int h = 0; h < 4; h++) mx[h] = fmaxf(mx[h], leaky02(alS[s * 4 + h] + aldi[h]));
    }
#pragma unroll
    for (int off = 32; off >= 1; off >>= 1)
#pragma unroll
      for (int h = 0; h < 4; h++) mx[h] = fmaxf(mx[h], __shfl_xor(mx[h], off));
    float m[4], exs[4];
#pragma unroll
    for (int h = 0; h < 4; h++) { m[h] = fmaxf(mx[h], esf[h]); exs[h] = __expf(esf[h] - m[h]); }

    const short* xhi = xhb + (size_t)i * HF;
    float acc0 = (h0a ? exs[0] : exs[1]) * bf2f(xhi[f0]);
    float acc1 = (h1a ? exs[1] : exs[2]) * bf2f(xhi[f1]);
    float acc2 = (h2a ? exs[2] : exs[3]) * bf2f(xhi[f2]);
    float acc3 = v3 ? exs[3] * bf2f(xhi[f3]) : 0.f;
    float zl[4] = {0.f, 0.f, 0.f, 0.f};

    for (int c0 = 0; c0 < deg; c0 += 64) {
      int cn = min(64, deg - c0);
      int s = 0;
      float ex0 = 0.f, ex1 = 0.f, ex2 = 0.f, ex3 = 0.f;
      if (lane < cn) {
        s = colidx[base + c0 + lane];
        ex0 = __expf(leaky02(alS[s * 4 + 0] + aldi[0]) - m[0]);
        ex1 = __expf(leaky02(alS[s * 4 + 1] + aldi[1]) - m[1]);
        ex2 = __expf(leaky02(alS[s * 4 + 2] + aldi[2]) - m[2]);
        ex3 = __expf(leaky02(alS[s * 4 + 3] + aldi[3]) - m[3]);
        zl[0] += ex0; zl[1] += ex1; zl[2] += ex2; zl[3] += ex3;
      }
      for (int jj = 0; jj < cn; jj += 4) {
        int sj[4]; float a0[4], a1[4], a2[4], a3[4];
#pragma unroll
        for (int q = 0; q < 4; q++) {
          int j2 = jj + q;
          int jc = (j2 < cn) ? j2 : (cn - 1);
          bool val = j2 < cn;
          sj[q] = __shfl(s, jc);
          a0[q] = val ? __shfl(ex0, jc) : 0.f;
          a1[q] = val ? __shfl(ex1, jc) : 0.f;
          a2[q] = val ? __shfl(ex2, jc) : 0.f;
          a3[q] = val ? __shfl(ex3, jc) : 0.f;
        }
        float g0[4], g1[4], g2[4], g3[4];
#pragma unroll
        for (int q = 0; q < 4; q++) {
          const short* xr = xhb + (size_t)sj[q] * HF;
          g0[q] = bf2f(xr[f0]);
          g1[q] = bf2f(xr[f1]);
          g2[q] = bf2f(xr[f2]);
          g3[q] = v3 ? bf2f(xr[f3]) : 0.f;
        }
#pragma unroll
        for (int q = 0; q < 4; q++) {
          acc0 += (h0a ? a0[q] : a1[q]) * g0[q];
          acc1 += (h1a ? a1[q] : a2[q]) * g1[q];
          acc2 += (h2a ? a2[q] : a3[q]) * g2[q];
          if (v3) acc3 += a3[q] * g3[q];
        }
      }
    }
#pragma unroll
    for (int off = 32; off >= 1; off >>= 1)
#pragma unroll
      for (int h = 0; h < 4; h++) zl[h] += __shfl_xor(zl[h], off);
    float z[4];
#pragma unroll
    for (int h = 0; h < 4; h++) z[h] = zl[h] + exs[h] + 1e-16f;

    float o0 = fmaxf(acc0 / (h0a ? z[0] : z[1]) + bi0, 0.f);
    float o1 = fmaxf(acc1 / (h1a ? z[1] : z[2]) + bi1, 0.f);
    float o2 = fmaxf(acc2 / (h2a ? z[2] : z[3]) + bi2, 0.f);
    float o3 = v3 ? fmaxf(acc3 / z[3] + bi3, 0.f) : 0.f;
    int b = batch[i];
    if (b != curb) {
      if (curb >= 0) {
        float* pg = pooled + (size_t)curb * POOLW;
        atomicAdd(&pg[f0], r0);
        atomicAdd(&pg[f1], r1);
        atomicAdd(&pg[f2], r2);
        if (v3) atomicAdd(&pg[f3], r3);
      }
      curb = b; r0 = o0; r1 = o1; r2 = o2; r3 = o3;
    } else {
      r0 += o0; r1 += o1; r2 += o2; r3 += o3;
    }
  }
  if (curb >= 0) {
    float* pg = pooled + (size_t)curb * POOLW;
    atomicAdd(&pg[f0], r0);
    atomicAdd(&pg[f1], r1);
    atomicAdd(&pg[f2], r2);
    if (v3) atomicAdd(&pg[f3], r3);
  }
}

// ---------------------------------------------------------------------------
// GIN (1): gather-sum agg = x + sum_neighbors x
// ---------------------------------------------------------------------------
__global__ __launch_bounds__(256) void k_ginagg(
    const float* __restrict__ x, const int* __restrict__ rp, const int* __restrict__ colidx,
    float* __restrict__ agg) {
  int wid = threadIdx.x >> 6, lane = threadIdx.x & 63;
  int i = blockIdx.x * 4 + wid;
  if (i >= N_NODES) return;
  int base = rp[i], deg = rp[i + 1] - base;
  float hk = (lane < FDIM) ? x[(size_t)i * FDIM + lane] : 0.f;
  int c = 0;
  for (; c + 4 <= deg; c += 4) {
    int s0 = colidx[base + c + 0];
    int s1 = colidx[base + c + 1];
    int s2 = colidx[base + c + 2];
    int s3 = colidx[base + c + 3];
    if (lane < FDIM) {
      float v0 = x[(size_t)s0 * FDIM + lane];
      float v1 = x[(size_t)s1 * FDIM + lane];
      float v2 = x[(size_t)s2 * FDIM + lane];
      float v3 = x[(size_t)s3 * FDIM + lane];
      hk += (v0 + v1) + (v2 + v3);
    }
  }
  for (; c < deg; c++) {
    int s = colidx[base + c];
    if (lane < FDIM) hk += x[(size_t)s * FDIM + lane];
  }
  if (lane < FDIM) agg[(size_t)i * FDIM + lane] = hk;
}

// ---------------------------------------------------------------------------
// GIN (2): h1g = relu(agg @ w1 + b1)
// ---------------------------------------------------------------------------
__global__ __launch_bounds__(256) void k_gin1(
    const float* __restrict__ agg, const float* __restrict__ w1, const float* __restrict__ b1,
    float* __restrict__ h1g) {
  __shared__ float As[64 * APAD];
  __shared__ float Ws[FDIM * 112];
  int m0 = blockIdx.x * 64;
  int t = threadIdx.x;
  for (int idx = t; idx < 64 * FDIM; idx += 256) {
    int m = idx / FDIM, k = idx % FDIM;
    int gm = m0 + m;
    As[m * APAD + k] = (gm < N_NODES) ? agg[(size_t)gm * FDIM + k] : 0.f;
  }
  for (int idx = t; idx < FDIM * 112; idx += 256) {
    int k = idx / 112, n = idx % 112;
    Ws[idx] = (n < F2) ? w1[k * F2 + n] : 0.f;
  }
  __syncthreads();
  int tx = t & 15, ty = t >> 4;
  int ms = tx * 4, ns = ty * 7;
  float acc[4][7];
#pragma unroll
  for (int i = 0; i < 4; i++)
#pragma unroll
    for (int j = 0; j < 7; j++) acc[i][j] = 0.f;
  for (int k = 0; k < FDIM; k++) {
    float a0 = As[(ms + 0) * APAD + k];
    float a1 = As[(ms + 1) * APAD + k];
    float a2 = As[(ms + 2) * APAD + k];
    float a3 = As[(ms + 3) * APAD + k];
    float b[7];
#pragma unroll
    for (int j = 0; j < 7; j++) b[j] = Ws[k * 112 + ns + j];
#pragma unroll
    for (int j = 0; j < 7; j++) {
      acc[0][j] += a0 * b[j];
      acc[1][j] += a1 * b[j];
      acc[2][j] += a2 * b[j];
      acc[3][j] += a3 * b[j];
    }
  }
#pragma unroll
  for (int i = 0; i < 4; i++) {
    int gm = m0 + ms + i;
    if (gm >= N_NODES) break;
#pragma unroll
    for (int j = 0; j < 7; j++) {
      int n = ns + j;
      if (n < F2) h1g[(size_t)gm * F2 + n] = fmaxf(acc[i][j] + b1[n], 0.f);
    }
  }
}

// ---------------------------------------------------------------------------
// GIN (3): h2 = relu(h1g @ w2 + b2) + pooled accumulation (LDS psum)
// ---------------------------------------------------------------------------
#define A2PAD 111
__global__ __launch_bounds__(256) void k_gin2(
    const float* __restrict__ h1g, const float* __restrict__ w2, const float* __restrict__ b2,
    const int* __restrict__ batch, float* __restrict__ pooled) {
  __shared__ float As[64 * A2PAD];
  __shared__ float Ws[F2 * 112];
  __shared__ float psum[4 * 112];
  int m0 = blockIdx.x * 64;
  int t = threadIdx.x;
  for (int idx = t; idx < 4 * 112; idx += 256) psum[idx] = 0.f;
  for (int idx = t; idx < 64 * F2; idx += 256) {
    int m = idx / F2, k = idx % F2;
    int gm = m0 + m;
    As[m * A2PAD + k] = (gm < N_NODES) ? h1g[(size_t)gm * F2 + k] : 0.f;
  }
  for (int idx = t; idx < F2 * 112; idx += 256) {
    int k = idx / 112, n = idx % 112;
    Ws[idx] = (n < F2) ? w2[k * F2 + n] : 0.f;
  }
  __syncthreads();
  int tx = t & 15, ty = t >> 4;
  int ms = tx * 4, ns = ty * 7;
  float acc[4][7];
#pragma unroll
  for (int i = 0; i < 4; i++)
#pragma unroll
    for (int j = 0; j < 7; j++) acc[i][j] = 0.f;
  for (int k = 0; k < F2; k++) {
    float a0 = As[(ms + 0) * A2PAD + k];
    float a1 = As[(ms + 1) * A2PAD + k];
    float a2 = As[(ms + 2) * A2PAD + k];
    float a3 = As[(ms + 3) * A2PAD + k];
    float b[7];
#pragma unroll
    for (int j = 0; j < 7; j++) b[j] = Ws[k * 112 + ns + j];
#pragma unroll
    for (int j = 0; j < 7; j++) {
      acc[0][j] += a0 * b[j];
      acc[1][j] += a1 * b[j];
      acc[2][j] += a2 * b[j];
      acc[3][j] += a3 * b[j];
    }
  }
  float b2n[7];
#pragma unroll
  for (int j = 0; j < 7; j++) {
    int n = ns + j;
    b2n[j] = (n < F2) ? b2[n] : 0.f;
  }
  int bmin = batch[m0];
  float pj[7];
#pragma unroll
  for (int j = 0; j < 7; j++) pj[j] = 0.f;
  int curb = -1;
#pragma unroll
  for (int i = 0; i < 4; i++) {
    int gm = m0 + ms + i;
    if (gm >= N_NODES) break;
    int b = batch[gm];
    if (b != curb) {
      if (curb >= 0) {
        int slot = curb - bmin;
        if (slot >= 0 && slot < 4) {
#pragma unroll
          for (int j = 0; j < 7; j++)
            if (ns + j < F2) atomicAdd(&psum[slot * 112 + ns + j], pj[j]);
        } else {
          float* pg = pooled + (size_t)curb * POOLW + HF;
#pragma unroll
          for (int j = 0; j < 7; j++)
            if (ns + j < F2) atomicAdd(&pg[ns + j], pj[j]);
        }
      }
      curb = b;
#pragma unroll
      for (int j = 0; j < 7; j++)
        pj[j] = (ns + j < F2) ? fmaxf(acc[i][j] + b2n[j], 0.f) : 0.f;
    } else {
#pragma unroll
      for (int j = 0; j < 7; j++)
        if (ns + j < F2) pj[j] += fmaxf(acc[i][j] + b2n[j], 0.f);
    }
  }
  if (curb >= 0) {
    int slot = curb - bmin;
    if (slot >= 0 && slot < 4) {
#pragma unroll
      for (int j = 0; j < 7; j++)
        if (ns + j < F2) atomicAdd(&psum[slot * 112 + ns + j], pj[j]);
    } else {
      float* pg = pooled + (size_t)curb * POOLW + HF;
#pragma unroll
      for (int j = 0; j < 7; j++)
        if (ns + j < F2) atomicAdd(&pg[ns + j], pj[j]);
    }
  }
  __syncthreads();
  for (int idx = t; idx < 4 * 112; idx += 256) {
    int slot = idx / 112, n = idx % 112;
    float v = psum[idx];
    int b = bmin + slot;
    if (n < F2 && b < BATCH && v != 0.f)
      atomicAdd(&pooled[(size_t)b * POOLW + HF + n], v);
  }
}

// ---------------------------------------------------------------------------
// EdgeConv v7: pipelined MFMA (double-buffer LDS, lgkmcnt-only barrier,
// next-tile prefetch in flight across the barrier).
// ---------------------------------------------------------------------------
#define ECH 25
__global__ __launch_bounds__(256) void k_ec(
    const float* __restrict__ U, const float* __restrict__ V,
    const float* __restrict__ w2, const float* __restrict__ b2,
    const int* __restrict__ rp, const int* __restrict__ colidx,
    const int* __restrict__ batch, float* __restrict__ pooled) {
  const int t = threadIdx.x;
  const int lane = t & 63, wid = t >> 6;
  const int n16 = lane & 15, quad = lane >> 4;
  const int nt = (wid == 3) ? 1 : 2;   // u-tile 7 is all-pad

  short8 Bh[2][4];
  for (int tt = 0; tt < 2; tt++) {
    int ucol = (wid * 2 + tt) * 16 + n16;
    for (int kc = 0; kc < 4; kc++) {
      short8 vh;
#pragma unroll
      for (int jv = 0; jv < 8; jv++) {
        int kk = kc * 32 + quad * 8 + jv;
        float w = (ucol < F2 && kk < F2) ? w2[kk * F2 + ucol] : 0.f;
        vh[jv] = f2bf(w);
      }
      Bh[tt][kc] = vh;
    }
  }
  float b2v[2];
#pragma unroll
  for (int tt = 0; tt < 2; tt++) {
    int u = (wid * 2 + tt) * 16 + n16;
    b2v[tt] = (u < F2) ? b2[u] : 0.f;
  }

  __shared__ short hs[2][16 * 16 * 8];
  union SU { short8 s; unsigned u[4]; };
  const int es = t & 15, kg = t >> 4;
  const int k0 = kg * 8;

  float sm0 = 0.f, sm1 = 0.f;
  int curb = -1;
  const int u0 = (wid * 2) * 16 + n16;
  const int u1 = (wid * 2 + 1) * 16 + n16;

  const int i0 = blockIdx.x * ECH;
  const int iend = min(i0 + ECH, N_NODES);

  int i = i0, base = 0, deg = 0;
  bool have = false;
  for (; i < iend; i++) {
    base = rp[i]; deg = rp[i + 1] - base;
    if (deg > 0) { have = true; break; }
  }
  float2 pv[4], pu[4];
  if (have) {
    const float2* up = (const float2*)(U + (size_t)i * F2 + k0);
#pragma unroll
    for (int p = 0; p < 4; p++) pu[p] = up[p];
    int s = colidx[base + ((es < deg) ? es : 0)];
    const float2* vp = (const float2*)(V + (size_t)s * F2 + k0);
#pragma unroll
    for (int p = 0; p < 4; p++) pv[p] = vp[p];
  }
  float Uc[8];
  float vmax0 = -1e30f, vmax1 = -1e30f;
  int tb = 0, parity = 0;
  while (have) {
    if (tb == 0) {
#pragma unroll
      for (int p = 0; p < 4; p++) { Uc[2 * p] = pu[p].x; Uc[2 * p + 1] = pu[p].y; }
    }
    SU w;
#pragma unroll
    for (int p = 0; p < 4; p++) {
      bool kv = (k0 + 2 * p) < F2;
      float h0 = kv ? fmaxf(Uc[2 * p] + pv[p].x, 0.f) : 0.f;
      float h1 = kv ? fmaxf(Uc[2 * p + 1] + pv[p].y, 0.f) : 0.f;
      w.u[p] = pk2(h0, h1);
    }
    int ni = i, ntb = tb + 1, nbase = base, ndeg = deg;
    bool nhave = true;
    if (ntb * 16 >= deg) {
      ntb = 0; nhave = false;
      for (ni = i + 1; ni < iend; ni++) {
        nbase = rp[ni]; ndeg = rp[ni + 1] - nbase;
        if (ndeg > 0) { nhave = true; break; }
      }
    }
    *(short8*)&hs[parity][(kg * 16 + es) * 8] = w.s;
    if (nhave) {
      if (ntb == 0) {
        const float2* up = (const float2*)(U + (size_t)ni * F2 + k0);
#pragma unroll
        for (int p = 0; p < 4; p++) pu[p] = up[p];
      }
      int eg2 = ntb * 16 + es;
      int s2 = colidx[nbase + ((eg2 < ndeg) ? eg2 : 0)];
      const float2* vp = (const float2*)(V + (size_t)s2 * F2 + k0);
#pragma unroll
      for (int p = 0; p < 4; p++) pv[p] = vp[p];
    }
    ldsbar();
    f32x4 a0 = {0.f, 0.f, 0.f, 0.f}, a1 = {0.f, 0.f, 0.f, 0.f};
#pragma unroll
    for (int kc = 0; kc < 4; kc++) {
      short8 af = *(const short8*)&hs[parity][((kc * 4 + quad) * 16 + n16) * 8];
      a0 = __builtin_amdgcn_mfma_f32_16x16x32_bf16(af, Bh[0][kc], a0, 0, 0, 0);
      if (nt > 1)
        a1 = __builtin_amdgcn_mfma_f32_16x16x32_bf16(af, Bh[1][kc], a1, 0, 0, 0);
    }
    float m0 = -1e30f, m1 = -1e30f;
#pragma unroll
    for (int r = 0; r < 4; r++) {
      int er = tb * 16 + quad * 4 + r;
      if (er < deg) { m0 = fmaxf(m0, a0[r]); m1 = fmaxf(m1, a1[r]); }
    }
    m0 = fmaxf(m0, __shfl_xor(m0, 16)); m0 = fmaxf(m0, __shfl_xor(m0, 32));
    m1 = fmaxf(m1, __shfl_xor(m1, 16)); m1 = fmaxf(m1, __shfl_xor(m1, 32));
    vmax0 = fmaxf(vmax0, m0);
    vmax1 = fmaxf(vmax1, m1);
    if (ni != i) {
      float o0 = fmaxf(vmax0 + b2v[0], 0.f);
      float o1 = fmaxf(vmax1 + b2v[1], 0.f);
      int b = batch[i];
      if (b != curb) {
        if (curb >= 0 && quad == 0) {
          float* pg = pooled + (size_t)curb * POOLW + HF + F2;
          if (u0 < F2) atomicAdd(&pg[u0], sm0);
          if (nt > 1 && u1 < F2) atomicAdd(&pg[u1], sm1);
        }
        curb = b; sm0 = o0; sm1 = o1;
      } else {
        sm0 += o0; sm1 += o1;
      }
      vmax0 = -1e30f; vmax1 = -1e30f;
    }
    i = ni; tb = ntb; base = nbase; deg = ndeg; have = nhave; parity ^= 1;
  }
  if (curb >= 0 && quad == 0) {
    float* pg = pooled + (size_t)curb * POOLW + HF + F2;
    if (u0 < F2) atomicAdd(&pg[u0], sm0);
    if (nt > 1 && u1 < F2) atomicAdd(&pg[u1], sm1);
  }
}

// ---------------------------------------------------------------------------
// mean-pool divide (counts from sorted-batch boundaries)
// ---------------------------------------------------------------------------
__global__ void k_pooldiv(float* __restrict__ pooled, const int* __restrict__ start) {
  int t = blockIdx.x * blockDim.x + threadIdx.x;
  if (t >= BATCH * POOLW) return;
  int b = t / POOLW;
  float c = (float)(start[b + 1] - start[b]);
  pooled[t] /= fmaxf(c, 1.f);
}

// ---------------------------------------------------------------------------
// Per-graph heads: block g computes all three 2-layer MLPs -> cat[g][384]
// ---------------------------------------------------------------------------
__global__ __launch_bounds__(256) void k_heads(
    const float* __restrict__ pooled,
    const float* __restrict__ fg1_w, const float* __restrict__ fg1_b,
    const float* __restrict__ fg2_w, const float* __restrict__ fg2_b,
    const float* __restrict__ fg3_w, const float* __restrict__ fg3_b,
    const float* __restrict__ fg4_w, const float* __restrict__ fg4_b,
    const float* __restrict__ fg5_w, const float* __restrict__ fg5_b,
    const float* __restrict__ fg6_w, const float* __restrict__ fg6_b,
    float* __restrict__ cat) {
  int g = blockIdx.x, t = threadIdx.x;
  __shared__ float in[POOLW];
  __shared__ float mid[256];
  for (int idx = t; idx < POOLW; idx += 256) in[idx] = pooled[(size_t)g * POOLW + idx];
  __syncthreads();
  const float* w1s[3] = {fg1_w, fg3_w, fg5_w};
  const float* b1s[3] = {fg1_b, fg3_b, fg5_b};
  const float* w2s[3] = {fg2_w, fg4_w, fg6_w};
  const float* b2s[3] = {fg2_b, fg4_b, fg6_b};
  const int off[4] = {0, HF, HF + F2, POOLW};
  for (int br = 0; br < 3; br++) {
    int kin = off[br + 1] - off[br];
    const float* iv = &in[off[br]];
    float a = b1s[br][t];
    const float* W = w1s[br];
    for (int k = 0; k < kin; k++) a += iv[k] * W[k * 256 + t];
    mid[t] = fmaxf(a, 0.f);
    __syncthreads();
    if (t < 128) {
      float b = b2s[br][t];
      const float* W2 = w2s[br];
      for (int k = 0; k < 256; k++) b += mid[k] * W2[k * 128 + t];
      cat[(size_t)g * 384 + br * 128 + t] = fmaxf(b, 0.f);
    }
    __syncthreads();
  }
}

// ---------------------------------------------------------------------------
// Final MLP: cat[384] -> 128 -> 64 -> 1 sigmoid, block per graph
// ---------------------------------------------------------------------------
__global__ __launch_bounds__(256) void k_final(
    const float* __restrict__ cat,
    const float* __restrict__ fc1_w, const float* __restrict__ fc1_b,
    const float* __restrict__ fc2_w, const float* __restrict__ fc2_b,
    const float* __restrict__ out_w, const float* __restrict__ out_b,
    float* __restrict__ out) {
  int g = blockIdx.x, t = threadIdx.x;
  __shared__ float hin[384];
  __shared__ float h1[128];
  __shared__ float h2[64];
  for (int idx = t; idx < 384; idx += 256) hin[idx] = cat[(size_t)g * 384 + idx];
  __syncthreads();
  if (t < 128) {
    float a = fc1_b[t];
    for (int k = 0; k < 384; k++) a += hin[k] * fc1_w[k * 128 + t];
    h1[t] = fmaxf(a, 0.f);
  }
  __syncthreads();
  if (t < 64) {
    float a = fc2_b[t];
    for (int k = 0; k < 128; k++) a += h1[k] * fc2_w[k * 64 + t];
    h2[t] = fmaxf(a, 0.f);
  }
  __syncthreads();
  if (t == 0) {
    float a = out_b[0];
    for (int k = 0; k < 64; k++) a += h2[k] * out_w[k];
    out[g] = 1.f / (1.f + __expf(-a));
  }
}

// ---------------------------------------------------------------------------
extern "C" void kernel_launch(void* const* d_in, const int* in_sizes, int n_in,
                              void* d_out, int out_size, void* d_ws, size_t ws_size,
                              hipStream_t stream) {
  const float* x      = (const float*)d_in[0];
  const int*   ei     = (const int*)d_in[1];
  const int*   batch  = (const int*)d_in[2];
  const float* gat_w  = (const float*)d_in[3];
  const float* asrc   = (const float*)d_in[4];
  const float* adst   = (const float*)d_in[5];
  const float* gat_b  = (const float*)d_in[6];
  const float* gin_w1 = (const float*)d_in[7];
  const float* gin_b1 = (const float*)d_in[8];
  const float* gin_w2 = (const float*)d_in[9];
  const float* gin_b2 = (const float*)d_in[10];
  const float* ec_w1  = (const float*)d_in[11];
  const float* ec_b1  = (const float*)d_in[12];
  const float* ec_w2  = (const float*)d_in[13];
  const float* ec_b2  = (const float*)d_in[14];
  const float* fg1_w = (const float*)d_in[15]; const float* fg1_b = (const float*)d_in[16];
  const float* fg2_w = (const float*)d_in[17]; const float* fg2_b = (const float*)d_in[18];
  const float* fg3_w = (const float*)d_in[19]; const float* fg3_b = (const float*)d_in[20];
  const float* fg4_w = (const float*)d_in[21]; const float* fg4_b = (const float*)d_in[22];
  const float* fg5_w = (const float*)d_in[23]; const float* fg5_b = (const float*)d_in[24];
  const float* fg6_w = (const float*)d_in[25]; const float* fg6_b = (const float*)d_in[26];
  const float* fc1_w = (const float*)d_in[27]; const float* fc1_b = (const float*)d_in[28];
  const float* fc2_w = (const float*)d_in[29]; const float* fc2_b = (const float*)d_in[30];
  const float* out_w = (const float*)d_in[31]; const float* out_b = (const float*)d_in[32];
  float* out = (float*)d_out;

  char* ws = (char*)d_ws;
  size_t off = 0;
  auto alloc = [&](size_t bytes) -> void* {
    void* p = ws + off;
    off = (off + bytes + 255) & ~(size_t)255;
    return p;
  };
  // --- zero region (one memset): histP | pooled ---
  size_t zoff0 = off;
  int*   histP  = (int*)alloc((size_t)N_NODES * PSTR * sizeof(int));  // 6.4 MB padded bins
  float* pooled = (float*)alloc((size_t)BATCH * POOLW * sizeof(float));
  size_t zbytes = off - zoff0;
  // --- rest ---
  int*   rp     = (int*)alloc((N_NODES + 1) * sizeof(int));
  int*   start  = (int*)alloc((BATCH + 1) * sizeof(int));
  int*   bsum   = (int*)alloc(256 * sizeof(int));
  int*   colidx = (int*)alloc(N_EDGES * sizeof(int));
  short* xhb    = (short*)alloc((size_t)N_NODES * HF * sizeof(short));
  float* alS    = (float*)alloc((size_t)N_NODES * 4 * sizeof(float));
  float* alD    = (float*)alloc((size_t)N_NODES * 4 * sizeof(float));
  float* Ubuf   = (float*)alloc((size_t)N_NODES * F2 * sizeof(float));
  float* Vbuf   = (float*)alloc((size_t)N_NODES * F2 * sizeof(float));
  float* cAl    = (float*)alloc(FDIM * 8 * sizeof(float));
  float* Wp     = (float*)alloc((size_t)FDIM * NPACK * sizeof(float));
  float* bpk    = (float*)alloc(NPACK * sizeof(float));
  float* cat    = (float*)alloc((size_t)BATCH * 384 * sizeof(float));
  (void)ws_size; (void)in_sizes; (void)n_in; (void)out_size;
  // GIN scratch aliases U/V (dead after k_ec; stream order serializes):
  float* agg = Ubuf;                            // 50000*53 floats
  float* h1g = Ubuf + (size_t)N_NODES * FDIM;   // 50000*106 floats (spills into Vbuf)

  hipMemsetAsync(ws + zoff0, 0, zbytes, stream);

  k_cal<<<1, 448, 0, stream>>>(gat_w, asrc, adst, cAl);
  k_prep<<<(FDIM * NPACK + 255) / 256, 256, 0, stream>>>(gat_w, ec_w1, ec_b1, cAl, Wp, bpk);
  k_gemm<<<((N_NODES + GM - 1) / GM) * 3, 256, 0, stream>>>(x, Wp, bpk,
                                                            xhb, Ubuf, Vbuf, alS, alD);
  k_hist<<<(N_EDGES + 255) / 256, 256, 0, stream>>>(ei, histP);
  k_bnd<<<(N_NODES + 255) / 256, 256, 0, stream>>>(batch, start);
  k_scan1<<<SCAN_BLOCKS, 256, 0, stream>>>(histP, rp, bsum);
  k_scan2<<<1, 256, 0, stream>>>(bsum);
  k_scan3<<<SCAN_BLOCKS, 256, 0, stream>>>(bsum, rp, histP);
  k_scatter<<<(N_EDGES + 255) / 256, 256, 0, stream>>>(ei, histP, colidx);

  k_gat<<<(N_NODES + GCH - 1) / GCH, 256, 0, stream>>>(xhb, alS, alD, gat_b, rp, colidx, batch, pooled);
  k_ec<<<(N_NODES + ECH - 1) / ECH, 256, 0, stream>>>(Ubuf, Vbuf, ec_w2, ec_b2, rp, colidx, batch, pooled);
  // GIN after k_ec (agg/h1g alias U/V)
  k_ginagg<<<(N_NODES + 3) / 4, 256, 0, stream>>>(x, rp, colidx, agg);
  k_gin1<<<(N_NODES + 63) / 64, 256, 0, stream>>>(agg, gin_w1, gin_b1, h1g);
  k_gin2<<<(N_NODES + 63) / 64, 256, 0, stream>>>(h1g, gin_w2, gin_b2, batch, pooled);

  k_pooldiv<<<(BATCH * POOLW + 255) / 256, 256, 0, stream>>>(pooled, start);

  k_heads<<<BATCH, 256, 0, stream>>>(pooled, fg1_w, fg1_b, fg2_w, fg2_b, fg3_w, fg3_b,
                                     fg4_w, fg4_b, fg5_w, fg5_b, fg6_w, fg6_b, cat);
  k_final<<<BATCH, 256, 0, stream>>>(cat, fc1_w, fc1_b, fc2_w, fc2_b, out_w, out_b, out);
}